// Round 5
// baseline (893.339 us; speedup 1.0000x reference)
//
#include <hip/hip_runtime.h>
#include <hip/hip_cooperative_groups.h>

namespace cg = cooperative_groups;

typedef unsigned long long u64;

#define EPSV 1e-5

__device__ __forceinline__ int imax(int a, int b) { return a > b ? a : b; }
__device__ __forceinline__ int iclamp(int v, int lo, int hi) { return v < lo ? lo : (v > hi ? hi : v); }

// threshold math — bit-identical to the proven bnpack kernels
__device__ __forceinline__ int2 thr_int(long long S1, long long S2, float gv, float bv, int count) {
    double m = (double)S1 / count;
    double var = (double)S2 / count - m * m;
    double sc = (double)gv / sqrt(var + EPSV);
    int2 r;
    if (sc == 0.0) r = make_int2(bv >= 0.f ? (int)0x80000000 : 0x7fffffff, 0);
    else {
        double t = m - (double)bv / sc;
        if (t > 1.0e9) t = 1.0e9;
        if (t < -1.0e9) t = -1.0e9;
        r = (sc > 0.0) ? make_int2((int)ceil(t), 0) : make_int2((int)floor(t), 1);
    }
    return r;
}

// ================= shared row-sliding binary conv core (layers 1..4), inb = LDS =================
template <int CW, int HIN, bool POOL, int WC, bool INTERIOR>
__device__ __forceinline__ void row_accum(const u64* __restrict__ inb,
                                          const u64* __restrict__ wpkT, int Co, int co,
                                          const int* yoff, const bool* ry, int* cnt) {
    constexpr int HP = POOL ? HIN / 2 : HIN;
    constexpr int WS = POOL ? 4 : 3;
    constexpr int NA = POOL ? 4 : 1;
#pragma unroll 1
    for (int w0 = 0; w0 < CW; w0 += WC) {
        u64 wg[9 * WC];
#pragma unroll
        for (int k = 0; k < 9; ++k)
#pragma unroll
            for (int w = 0; w < WC; ++w)
                wg[k * WC + w] = wpkT[(size_t)(k * CW + w0 + w) * Co + co];
        u64 cur[WS][WS][WC];
#pragma unroll
        for (int d = 0; d < WS; ++d) {
            int cc = d - 1;
            int ccc = cc < 0 ? 0 : cc;
#pragma unroll
            for (int r = 0; r < WS; ++r) {
                const u64* p = inb + yoff[r] + ccc * CW + w0;
                if (WC == 1) {
                    cur[r][d][0] = p[0];
                } else {
                    cur[r][d][0] = p[0];
                    cur[r][d][1] = p[1];
                }
            }
        }
#pragma unroll
        for (int xp = 0; xp < HP; ++xp) {
            if constexpr (POOL) {
#pragma unroll
                for (int py = 0; py < 2; ++py)
#pragma unroll
                    for (int qx = 0; qx < 2; ++qx)
#pragma unroll
                        for (int ky = 0; ky < 3; ++ky)
#pragma unroll
                            for (int kx = 0; kx < 3; ++kx) {
                                int d = qx + kx;
                                int cc = 2 * xp + d - 1;
                                if (cc >= 0 && cc < HIN) {
#pragma unroll
                                    for (int w = 0; w < WC; ++w) {
                                        int pc = (int)__popcll(cur[py + ky][d][w] ^
                                                               wg[(ky * 3 + kx) * WC + w]);
                                        if constexpr (INTERIOR)
                                            cnt[xp * NA + py * 2 + qx] += pc;
                                        else
                                            cnt[xp * NA + py * 2 + qx] += ry[py + ky] ? pc : 0;
                                    }
                                }
                            }
            } else {
#pragma unroll
                for (int ky = 0; ky < 3; ++ky)
#pragma unroll
                    for (int kx = 0; kx < 3; ++kx) {
                        int cc = xp + kx - 1;
                        if (cc >= 0 && cc < HIN) {
#pragma unroll
                            for (int w = 0; w < WC; ++w) {
                                int pc = (int)__popcll(cur[ky][kx][w] ^
                                                       wg[(ky * 3 + kx) * WC + w]);
                                if constexpr (INTERIOR)
                                    cnt[xp] += pc;
                                else
                                    cnt[xp] += ry[ky] ? pc : 0;
                            }
                        }
                    }
            }
            if (xp < HP - 1) {
                if constexpr (POOL) {
#pragma unroll
                    for (int r = 0; r < WS; ++r)
#pragma unroll
                        for (int w = 0; w < WC; ++w) {
                            cur[r][0][w] = cur[r][2][w];
                            cur[r][1][w] = cur[r][3][w];
                        }
#pragma unroll
                    for (int dd = 2; dd < 4; ++dd) {
                        int cc = 2 * (xp + 1) + dd - 1;
                        int ccc = cc >= HIN ? HIN - 1 : cc;
#pragma unroll
                        for (int r = 0; r < WS; ++r) {
                            const u64* p = inb + yoff[r] + ccc * CW + w0;
                            if (WC == 1) {
                                cur[r][dd][0] = p[0];
                            } else {
                                cur[r][dd][0] = p[0];
                                cur[r][dd][1] = p[1];
                            }
                        }
                    }
                } else {
#pragma unroll
                    for (int r = 0; r < WS; ++r)
#pragma unroll
                        for (int w = 0; w < WC; ++w) {
                            cur[r][0][w] = cur[r][1][w];
                            cur[r][1][w] = cur[r][2][w];
                        }
                    int cc = xp + 2;
                    int ccc = cc >= HIN ? HIN - 1 : cc;
#pragma unroll
                    for (int r = 0; r < WS; ++r) {
                        const u64* p = inb + yoff[r] + ccc * CW + w0;
                        if (WC == 1) {
                            cur[r][2][0] = p[0];
                        } else {
                            cur[r][2][0] = p[0];
                            cur[r][2][1] = p[1];
                        }
                    }
                }
            }
        }
    }
}

// #####################################################################################
// #####################  FALLBACK: round-3 multi-kernel pipeline  #####################
// #####################################################################################

struct PrepArgs {
    const float* src[10];
    u64* dst[10];
    int CW[10];
    int Co[10];
    int taps[10];
    int rowbase[11];
    u64* accs;
    int naccs;
};

__global__ __launch_bounds__(256) void prep_kernel(PrepArgs a) {
    __shared__ float buf[4608];
    const int blk = blockIdx.x;
    int z = blk * 19 + threadIdx.x;
    if (threadIdx.x < 19 && z < a.naccs) a.accs[z] = 0ULL;

    int l = 0;
    while (l < 9 && blk >= a.rowbase[l + 1]) ++l;
    const int row = blk - a.rowbase[l];
    const int CW = a.CW[l];
    const int taps = a.taps[l];
    const int nf = CW * 64 * taps;
    const float* srow = a.src[l] + (size_t)row * nf;
    for (int i = threadIdx.x; i < nf; i += 256) buf[i] = srow[i];
    __syncthreads();
    const int t = threadIdx.x;
    if (t < taps * CW) {
        u64 bits = 0;
        if (taps == 9) {
            int k = t % 9, w = t / 9;
            for (int j = 0; j < 64; ++j) bits |= (u64)(buf[(w * 64 + j) * 9 + k] >= 0.f) << j;
            a.dst[l][(size_t)(k * CW + w) * a.Co[l] + row] = bits;
        } else {
            for (int j = 0; j < 64; ++j) bits |= (u64)(buf[t * 64 + j] >= 0.f) << j;
            a.dst[l][(size_t)row * CW + t] = bits;
        }
    }
}

__global__ __launch_bounds__(256) void conv0_lane(const float* __restrict__ x,
                                                  const float* __restrict__ wgt,
                                                  float* __restrict__ out,
                                                  double* __restrict__ dacc) {
    const int lane = threadIdx.x & 63;
    const int wave = threadIdx.x >> 6;
    float ws[27];
#pragma unroll
    for (int j = 0; j < 27; ++j) ws[j] = (wgt[lane * 27 + j] >= 0.f) ? 1.f : -1.f;

    const int gp0 = blockIdx.x * 32;
    const int n = gp0 >> 8;
    const int ypA = (gp0 >> 4) & 15;
    const int yb = 2 * ypA - 1;

    __shared__ float simg[3][6][34];
    const float* xb = x + (size_t)n * 3072;
    for (int t = threadIdx.x; t < 612; t += 256) {
        int ci = t / 204;
        int rem = t % 204;
        int r = rem / 34;
        int cc = rem % 34;
        int yy = yb + r;
        int xx = cc - 1;
        float v = 0.f;
        if ((unsigned)yy < 32u && (unsigned)xx < 32u) v = xb[(ci * 32 + yy) * 32 + xx];
        simg[ci][r][cc] = v;
    }
    __syncthreads();

    double s1 = 0.0, s2 = 0.0;
#pragma unroll 2
    for (int pi = 0; pi < 8; ++pi) {
        const int lp = wave * 8 + pi;
        const int gp = gp0 + lp;
        const int xp = lp & 15;
        const int rbase = 2 * (lp >> 4);
        const int cbase = 2 * xp;
        float win[3][4][4];
#pragma unroll
        for (int ci = 0; ci < 3; ++ci)
#pragma unroll
            for (int r = 0; r < 4; ++r)
#pragma unroll
                for (int c = 0; c < 4; ++c) win[ci][r][c] = simg[ci][rbase + r][cbase + c];
        float a00 = 0.f, a01 = 0.f, a10 = 0.f, a11 = 0.f;
#pragma unroll
        for (int ci = 0; ci < 3; ++ci)
#pragma unroll
            for (int ky = 0; ky < 3; ++ky)
#pragma unroll
                for (int kx = 0; kx < 3; ++kx) {
                    float wv = ws[ci * 9 + ky * 3 + kx];
                    a00 += win[ci][ky][kx] * wv;
                    a01 += win[ci][ky][kx + 1] * wv;
                    a10 += win[ci][ky + 1][kx] * wv;
                    a11 += win[ci][ky + 1][kx + 1] * wv;
                }
        float val = fmaxf(fmaxf(a00, a01), fmaxf(a10, a11));
        out[(size_t)gp * 64 + lane] = val;
        s1 += (double)val;
        s2 += (double)val * (double)val;
    }
    __shared__ double sh1[4][64], sh2[4][64];
    sh1[wave][lane] = s1;
    sh2[wave][lane] = s2;
    __syncthreads();
    if (threadIdx.x < 64) {
        double t1 = 0.0, t2 = 0.0;
#pragma unroll
        for (int r = 0; r < 4; ++r) { t1 += sh1[r][threadIdx.x]; t2 += sh2[r][threadIdx.x]; }
        double* sh = dacc + (size_t)(blockIdx.x & 7) * 1024;
        atomicAdd(&sh[2 * threadIdx.x], t1);
        atomicAdd(&sh[2 * threadIdx.x + 1], t2);
    }
}

__global__ __launch_bounds__(256) void bnpack_i(const short* __restrict__ in,
                                                const u64* __restrict__ iacc,
                                                const float* __restrict__ g,
                                                const float* __restrict__ b,
                                                u64* __restrict__ act, int Co, int wshift,
                                                int count) {
    __shared__ int2 sthr[520];
    for (int i = threadIdx.x; i < Co; i += 256) {
        long long S1 = 0, S2 = 0;
#pragma unroll
        for (int s = 0; s < 8; ++s) {
            S1 += (long long)iacc[s * 1024 + 2 * i];
            S2 += (long long)iacc[s * 1024 + 2 * i + 1];
        }
        sthr[(i >> 6) * 65 + (i & 63)] = thr_int(S1, S2, g[i], b[i], count);
    }
    __syncthreads();
    int tid = blockIdx.x * 256 + threadIdx.x;
    int part = tid & 3;
    int word = tid >> 2;
    int w = word & ((1 << wshift) - 1);
    int pix = word >> wshift;
    const int4* r4 = (const int4*)(in + (size_t)pix * Co + (w << 6) + part * 16);
    u64 bits = 0;
#pragma unroll
    for (int q = 0; q < 2; ++q) {
        int4 v = r4[q];
        int words4[4] = {v.x, v.y, v.z, v.w};
#pragma unroll
        for (int u = 0; u < 4; ++u) {
#pragma unroll
            for (int h = 0; h < 2; ++h) {
                int c = part * 16 + q * 8 + u * 2 + h;
                int val = (int)(short)((h == 0) ? (words4[u] & 0xffff) : ((unsigned)words4[u] >> 16));
                int2 t = sthr[w * 65 + c];
                bool bit = t.y ? (val <= t.x) : (val >= t.x);
                bits |= (u64)bit << c;
            }
        }
    }
    bits |= __shfl_xor(bits, 1);
    bits |= __shfl_xor(bits, 2);
    if (part == 0) act[word] = bits;
}

template <int CW, int HIN, bool POOL, int WC, bool FIRST>
__global__ __launch_bounds__(256) void bconv_row_f(const void* __restrict__ inprev,
                                                   const void* __restrict__ pstats,
                                                   const float* __restrict__ pg,
                                                   const float* __restrict__ pb, int pcount,
                                                   const u64* __restrict__ wpkT,
                                                   short* __restrict__ out,
                                                   u64* __restrict__ iacc, int Co) {
    constexpr int HP = POOL ? HIN / 2 : HIN;
    constexpr int WS = POOL ? 4 : 3;
    constexpr int NA = POOL ? 4 : 1;
    constexpr int ROWS = POOL ? 10 : 6;
    constexpr int Ci = CW * 64;
    __shared__ __align__(16) u64 sU[ROWS * HIN * CW];
    __shared__ int2 sthr[CW * 65];
    __shared__ float2 sthf[64];

    if constexpr (FIRST) {
        if (threadIdx.x < 64) {
            const double* dacc = (const double*)pstats;
            int i = threadIdx.x;
            double S1 = 0.0, S2 = 0.0;
#pragma unroll
            for (int s = 0; s < 8; ++s) {
                S1 += dacc[s * 1024 + 2 * i];
                S2 += dacc[s * 1024 + 2 * i + 1];
            }
            double m = S1 / pcount;
            double var = S2 / pcount - m * m;
            double sc = (double)pg[i] / sqrt(var + EPSV);
            float2 r;
            if (sc == 0.0) r = make_float2(pb[i] >= 0.f ? -3.0e38f : 3.0e38f, 1.f);
            else {
                double t = m - (double)pb[i] / sc;
                r = make_float2((float)t, sc > 0.0 ? 1.f : -1.f);
            }
            sthf[i] = r;
        }
    } else {
        const u64* pacc = (const u64*)pstats;
        for (int i = threadIdx.x; i < Ci; i += 256) {
            long long S1 = 0, S2 = 0;
#pragma unroll
            for (int s = 0; s < 8; ++s) {
                S1 += (long long)pacc[s * 1024 + 2 * i];
                S2 += (long long)pacc[s * 1024 + 2 * i + 1];
            }
            sthr[(i >> 6) * 65 + (i & 63)] = thr_int(S1, S2, pg[i], pb[i], pcount);
        }
    }
    __syncthreads();

    const int bi = blockIdx.x;
    constexpr int BPN = HP / 4;
    const int n = bi / BPN;
    const int yp0 = (bi % BPN) * 4;
    const int ylo = imax(0, (POOL ? 2 * yp0 : yp0) - 1);
    const int yhiU = POOL ? (2 * yp0 + 8) : (yp0 + 4);
    const int yhi = yhiU > HIN - 1 ? HIN - 1 : yhiU;
    const int nrows = yhi - ylo + 1;
    const int nw = nrows * HIN * CW;

    if constexpr (FIRST) {
        const float* src = (const float*)inprev;
        for (int t = threadIdx.x; t < nw; t += 256) {
            int x = t % HIN;
            int yr = t / HIN;
            int y = ylo + yr;
            const float4* p = (const float4*)(src + (size_t)((n * 16 + y) * 16 + x) * 64);
            u64 bits = 0;
#pragma unroll
            for (int q = 0; q < 16; ++q) {
                float4 v = p[q];
                float vv[4] = {v.x, v.y, v.z, v.w};
#pragma unroll
                for (int u = 0; u < 4; ++u) {
                    int c = q * 4 + u;
                    float2 th = sthf[c];
                    bool bit = (th.y > 0.f) ? (vv[u] >= th.x) : (vv[u] <= th.x);
                    bits |= (u64)bit << c;
                }
            }
            sU[t] = bits;
        }
    } else {
        const short* src = (const short*)inprev;
        for (int t = threadIdx.x; t < nw; t += 256) {
            int w = t % CW;
            int x = (t / CW) % HIN;
            int yr = t / (HIN * CW);
            int y = ylo + yr;
            const int4* p = (const int4*)(src + (size_t)((n * HIN + y) * HIN + x) * Ci + w * 64);
            u64 bits = 0;
#pragma unroll
            for (int q = 0; q < 8; ++q) {
                int4 v = p[q];
                int wd[4] = {v.x, v.y, v.z, v.w};
#pragma unroll
                for (int u = 0; u < 4; ++u) {
#pragma unroll
                    for (int h = 0; h < 2; ++h) {
                        int j = q * 8 + u * 2 + h;
                        int val = (int)(short)((h == 0) ? (wd[u] & 0xffff) : ((unsigned)wd[u] >> 16));
                        int2 th = sthr[w * 65 + j];
                        bool bit = th.y ? (val <= th.x) : (val >= th.x);
                        bits |= (u64)bit << j;
                    }
                }
            }
            sU[t] = bits;
        }
    }
    __syncthreads();

    const int lane = threadIdx.x & 63;
    const int wave = threadIdx.x >> 6;
    const int co = blockIdx.y * 64 + lane;
    const int yp = yp0 + wave;
    const int grow = n * HP + yp;
    const int y0 = (POOL ? 2 * yp : yp) - 1;
    int yoff[WS];
    bool ry[WS];
#pragma unroll
    for (int r = 0; r < WS; ++r) {
        int y = y0 + r;
        ry[r] = (unsigned)y < (unsigned)HIN;
        int yc = iclamp(y, 0, HIN - 1);
        yoff[r] = (yc - ylo) * (HIN * CW);
    }
    int cnt[HP * NA];
#pragma unroll
    for (int i = 0; i < HP * NA; ++i) cnt[i] = 0;

    if (yp > 0 && yp < HP - 1)
        row_accum<CW, HIN, POOL, WC, true>(sU, wpkT, Co, co, yoff, ry, cnt);
    else
        row_accum<CW, HIN, POOL, WC, false>(sU, wpkT, Co, co, yoff, ry, cnt);

    const int nr0 = (int)ry[0] + (int)ry[1] + (int)ry[2];
    const int nr1 = POOL ? ((int)ry[1] + (int)ry[2] + (int)ry[WS - 1]) : 0;

    int s1 = 0;
    long long s2 = 0;
    short* orow = out + (size_t)grow * HP * Co + co;
#pragma unroll
    for (int xp = 0; xp < HP; ++xp) {
        int ival;
        if constexpr (POOL) {
            int best = -2147483647;
#pragma unroll
            for (int py = 0; py < 2; ++py) {
                const int nrv = py ? nr1 : nr0;
#pragma unroll
                for (int qx = 0; qx < 2; ++qx) {
                    int ncols = 3;
                    if (xp == 0 && qx == 0) ncols = 2;
                    if (xp == HP - 1 && qx == 1) ncols = 2;
                    int v = 64 * CW * nrv * ncols - 2 * cnt[xp * NA + py * 2 + qx];
                    best = imax(best, v);
                }
            }
            ival = best;
        } else {
            const int ncols = (xp == 0 || xp == HIN - 1) ? 2 : 3;
            ival = 64 * CW * nr0 * ncols - 2 * cnt[xp];
        }
        orow[(size_t)xp * Co] = (short)ival;
        s1 += ival;
        s2 += (long long)ival * ival;
    }

    __shared__ u64 sacc[128];
    if (threadIdx.x < 128) sacc[threadIdx.x] = 0ULL;
    __syncthreads();
    atomicAdd(&sacc[lane], (u64)(long long)s1);
    atomicAdd(&sacc[64 + lane], (u64)s2);
    __syncthreads();
    u64* sh = iacc + (size_t)(blockIdx.x & 7) * 1024;
    if (threadIdx.x < 64)
        atomicAdd(&sh[2 * (blockIdx.y * 64 + threadIdx.x)], sacc[threadIdx.x]);
    else if (threadIdx.x < 128)
        atomicAdd(&sh[2 * (blockIdx.y * 64 + threadIdx.x - 64) + 1], sacc[threadIdx.x]);
}

template <int CW, int HIN, bool POOL>
__global__ __launch_bounds__(256) void bconv_tiny_f(const short* __restrict__ inprev,
                                                    const u64* __restrict__ pacc,
                                                    const float* __restrict__ pg,
                                                    const float* __restrict__ pb, int pcount,
                                                    const u64* __restrict__ wpkT,
                                                    short* __restrict__ out,
                                                    u64* __restrict__ iacc, int Co) {
    constexpr int NPX = HIN * HIN;
    constexpr int HP = POOL ? HIN / 2 : HIN;
    constexpr int Ci = CW * 64;
    __shared__ int2 sthr[CW * 65];
    __shared__ u64 sU[4][NPX * CW];

    for (int i = threadIdx.x; i < Ci; i += 256) {
        long long S1 = 0, S2 = 0;
#pragma unroll
        for (int s = 0; s < 8; ++s) {
            S1 += (long long)pacc[s * 1024 + 2 * i];
            S2 += (long long)pacc[s * 1024 + 2 * i + 1];
        }
        sthr[(i >> 6) * 65 + (i & 63)] = thr_int(S1, S2, pg[i], pb[i], pcount);
    }
    __syncthreads();

    const int nbase = blockIdx.x * 4;
    for (int t = threadIdx.x; t < 4 * NPX * CW; t += 256) {
        int img = t / (NPX * CW);
        int rem = t % (NPX * CW);
        int w = rem % CW;
        int i = rem / CW;
        const int4* p = (const int4*)(inprev + (size_t)((nbase + img) * NPX + i) * Ci + w * 64);
        u64 bits = 0;
#pragma unroll
        for (int q = 0; q < 8; ++q) {
            int4 v = p[q];
            int wd[4] = {v.x, v.y, v.z, v.w};
#pragma unroll
            for (int u = 0; u < 4; ++u) {
#pragma unroll
                for (int h = 0; h < 2; ++h) {
                    int j = q * 8 + u * 2 + h;
                    int val = (int)(short)((h == 0) ? (wd[u] & 0xffff) : ((unsigned)wd[u] >> 16));
                    int2 th = sthr[w * 65 + j];
                    bool bit = th.y ? (val <= th.x) : (val >= th.x);
                    bits |= (u64)bit << j;
                }
            }
        }
        sU[img][i * CW + w] = bits;
    }
    __syncthreads();

    const int lane = threadIdx.x & 63;
    const int co = blockIdx.y * 64 + lane;
    const int n = nbase + (threadIdx.x >> 6);
    const u64* inb = sU[threadIdx.x >> 6];
    int cnt[NPX];
#pragma unroll
    for (int i = 0; i < NPX; ++i) cnt[i] = 0;

#pragma unroll 2
    for (int w = 0; w < CW; ++w) {
        u64 win[NPX];
#pragma unroll
        for (int i = 0; i < NPX; ++i) win[i] = inb[i * CW + w];
#pragma unroll
        for (int k = 0; k < 9; ++k) {
            u64 wb = wpkT[(size_t)(k * CW + w) * Co + co];
            const int ky = k / 3, kx = k % 3;
#pragma unroll
            for (int py = 0; py < HIN; ++py)
#pragma unroll
                for (int px = 0; px < HIN; ++px) {
                    const int yy = py + ky - 1, xx = px + kx - 1;
                    if (yy >= 0 && yy < HIN && xx >= 0 && xx < HIN)
                        cnt[py * HIN + px] += (int)__popcll(win[yy * HIN + xx] ^ wb);
                }
        }
    }

    int fin[NPX];
#pragma unroll
    for (int py = 0; py < HIN; ++py)
#pragma unroll
        for (int px = 0; px < HIN; ++px) {
            const int nk = ((py == 0 || py == HIN - 1) ? 2 : 3) *
                           ((px == 0 || px == HIN - 1) ? 2 : 3);
            fin[py * HIN + px] = 64 * CW * nk - 2 * cnt[py * HIN + px];
        }

    short vals[HP * HP];
    if constexpr (POOL) {
#pragma unroll
        for (int py = 0; py < HP; ++py)
#pragma unroll
            for (int px = 0; px < HP; ++px)
                vals[py * HP + px] = (short)imax(
                    imax(fin[(2 * py) * HIN + 2 * px], fin[(2 * py) * HIN + 2 * px + 1]),
                    imax(fin[(2 * py + 1) * HIN + 2 * px], fin[(2 * py + 1) * HIN + 2 * px + 1]));
    } else {
#pragma unroll
        for (int i = 0; i < NPX; ++i) vals[i] = (short)fin[i];
    }
#pragma unroll
    for (int p = 0; p < HP * HP; ++p) out[(size_t)(n * HP * HP + p) * Co + co] = vals[p];

    long long s1 = 0, s2 = 0;
#pragma unroll
    for (int p = 0; p < HP * HP; ++p) {
        s1 += vals[p];
        s2 += (long long)vals[p] * vals[p];
    }
    __shared__ u64 sacc[128];
    if (threadIdx.x < 128) sacc[threadIdx.x] = 0ULL;
    __syncthreads();
    atomicAdd(&sacc[lane], (u64)s1);
    atomicAdd(&sacc[64 + lane], (u64)s2);
    __syncthreads();
    u64* sh = iacc + (size_t)(blockIdx.x & 7) * 1024;
    if (threadIdx.x < 64)
        atomicAdd(&sh[2 * (blockIdx.y * 64 + threadIdx.x)], sacc[threadIdx.x]);
    else if (threadIdx.x < 128)
        atomicAdd(&sh[2 * (blockIdx.y * 64 + threadIdx.x - 64) + 1], sacc[threadIdx.x]);
}

__global__ __launch_bounds__(256) void lin_kernel(const u64* __restrict__ hp,
                                                  const u64* __restrict__ wp,
                                                  const float* __restrict__ lb,
                                                  const float* __restrict__ g,
                                                  const float* __restrict__ bta,
                                                  u64* __restrict__ op) {
    int o = blockIdx.x;
    int n = threadIdx.x;
    const u64* hr = hp + n * 8;
    const u64* wr = wp + o * 8;
    int s = 0;
#pragma unroll
    for (int w = 0; w < 8; ++w) s += (int)__popcll(hr[w] ^ wr[w]);
    float val = (float)(512 - 2 * s) + lb[o];
    __shared__ double sh1[256], sh2[256];
    sh1[n] = (double)val;
    sh2[n] = (double)val * (double)val;
    __syncthreads();
    for (int st = 128; st > 0; st >>= 1) {
        if (n < st) {
            sh1[n] += sh1[n + st];
            sh2[n] += sh2[n + st];
        }
        __syncthreads();
    }
    __shared__ float sm, siv;
    if (n == 0) {
        double m = sh1[0] / 256.0;
        double var = sh2[0] / 256.0 - m * m;
        sm = (float)m;
        siv = (float)(1.0 / sqrt(var + EPSV));
    }
    __syncthreads();
    float zz = g[o] * (val - sm) * siv + bta[o];
    if (zz >= 0.f) atomicOr(&op[(size_t)n * 8 + (o >> 6)], 1ULL << (o & 63));
}

__global__ __launch_bounds__(256) void lin2_lsm(const u64* __restrict__ hp,
                                                const u64* __restrict__ wp,
                                                const float* __restrict__ lb,
                                                const float* __restrict__ g,
                                                const float* __restrict__ bta,
                                                float* __restrict__ out) {
    const int n = threadIdx.x;
    const int lane = n & 63;
    const int wave = n >> 6;
    u64 h[8];
#pragma unroll
    for (int w = 0; w < 8; ++w) h[w] = hp[n * 8 + w];
    float v[10];
#pragma unroll
    for (int o = 0; o < 10; ++o) {
        int s = 0;
#pragma unroll
        for (int w = 0; w < 8; ++w) s += (int)__popcll(h[w] ^ wp[o * 8 + w]);
        v[o] = (float)(512 - 2 * s) + lb[o];
    }
    __shared__ double w1[4][10], w2[4][10];
#pragma unroll
    for (int o = 0; o < 10; ++o) {
        double a = (double)v[o];
        double b = a * a;
#pragma unroll
        for (int off = 32; off > 0; off >>= 1) {
            a += __shfl_xor(a, off);
            b += __shfl_xor(b, off);
        }
        if (lane == 0) {
            w1[wave][o] = a;
            w2[wave][o] = b;
        }
    }
    __syncthreads();
    float z[10];
#pragma unroll
    for (int o = 0; o < 10; ++o) {
        double S1 = w1[0][o] + w1[1][o] + w1[2][o] + w1[3][o];
        double S2 = w2[0][o] + w2[1][o] + w2[2][o] + w2[3][o];
        double m = S1 / 256.0;
        double var = S2 / 256.0 - m * m;
        float sm = (float)m;
        float siv = (float)(1.0 / sqrt(var + EPSV));
        z[o] = g[o] * (v[o] - sm) * siv + bta[o];
    }
    float mx = z[0];
#pragma unroll
    for (int o = 1; o < 10; ++o) mx = fmaxf(mx, z[o]);
    float se = 0.f;
#pragma unroll
    for (int o = 0; o < 10; ++o) se += expf(z[o] - mx);
    float ls = logf(se);
#pragma unroll
    for (int o = 0; o < 10; ++o) out[n * 10 + o] = z[o] - mx - ls;
}

// #####################################################################################
// #############################  MEGA (cooperative) path  #############################
// #####################################################################################

struct MegaArgs {
    const float* psrc[10];
    u64* pdst[10];
    int pCW[10];
    int pCo[10];
    int ptaps[10];
    int prow[11];
    u64* accs;
    int naccs;
    const float* x;
    const float* cw0;
    float* out0;
    const float* cg[8];
    const float* ct[8];
    u64* wpkT[8];
    short* i16A;
    short* i16B;
    u64* act7;
    u64* wpl[3];
    const float* lb[3];
    const float* lg[3];
    const float* lt[3];
    u64* fcs0;
    u64* fcs1;
    float* out;
};

template <int CW, int HIN, bool POOL, int WC, bool FIRST, int NBX, int NBY>
__device__ void bconv_row_stage(const void* inprev, const void* pstats,
                                const float* pg, const float* pb, int pcount,
                                const u64* __restrict__ wpkT, short* __restrict__ out,
                                u64* __restrict__ iacc, int Co, char* smem) {
    constexpr int HP = POOL ? HIN / 2 : HIN;
    constexpr int WS = POOL ? 4 : 3;
    constexpr int NA = POOL ? 4 : 1;
    constexpr int Ci = CW * 64;
    int2* sthr = (int2*)smem;
    float2* sthf = (float2*)smem;
    u64* sU = (u64*)(smem + 4608);
    u64* sacc = (u64*)(smem + 7680);

    if constexpr (FIRST) {
        if (threadIdx.x < 64) {
            const double* dacc = (const double*)pstats;
            int i = threadIdx.x;
            double S1 = 0.0, S2 = 0.0;
#pragma unroll
            for (int s = 0; s < 8; ++s) {
                S1 += dacc[s * 1024 + 2 * i];
                S2 += dacc[s * 1024 + 2 * i + 1];
            }
            double m = S1 / pcount;
            double var = S2 / pcount - m * m;
            double sc = (double)pg[i] / sqrt(var + EPSV);
            float2 r;
            if (sc == 0.0) r = make_float2(pb[i] >= 0.f ? -3.0e38f : 3.0e38f, 1.f);
            else {
                double t = m - (double)pb[i] / sc;
                r = make_float2((float)t, sc > 0.0 ? 1.f : -1.f);
            }
            sthf[i] = r;
        }
    } else {
        const u64* pacc = (const u64*)pstats;
        for (int i = threadIdx.x; i < Ci; i += 256) {
            long long S1 = 0, S2 = 0;
#pragma unroll
            for (int s = 0; s < 8; ++s) {
                S1 += (long long)pacc[s * 1024 + 2 * i];
                S2 += (long long)pacc[s * 1024 + 2 * i + 1];
            }
            sthr[(i >> 6) * 65 + (i & 63)] = thr_int(S1, S2, pg[i], pb[i], pcount);
        }
    }

    for (int vb = blockIdx.x; vb < NBX * NBY; vb += gridDim.x) {
        __syncthreads();
        const int bx = vb % NBX;
        const int by = vb / NBX;
        constexpr int BPN = HP / 4;
        const int n = bx / BPN;
        const int yp0 = (bx % BPN) * 4;
        const int ylo = imax(0, (POOL ? 2 * yp0 : yp0) - 1);
        const int yhiU = POOL ? (2 * yp0 + 8) : (yp0 + 4);
        const int yhi = yhiU > HIN - 1 ? HIN - 1 : yhiU;
        const int nrows = yhi - ylo + 1;
        const int nw = nrows * HIN * CW;

        if constexpr (FIRST) {
            const float* src = (const float*)inprev;
            for (int t = threadIdx.x; t < nw; t += 256) {
                int x = t % HIN;
                int yr = t / HIN;
                int y = ylo + yr;
                const float4* p = (const float4*)(src + (size_t)((n * 16 + y) * 16 + x) * 64);
                u64 bits = 0;
#pragma unroll
                for (int q = 0; q < 16; ++q) {
                    float4 v = p[q];
                    float vv[4] = {v.x, v.y, v.z, v.w};
#pragma unroll
                    for (int u = 0; u < 4; ++u) {
                        int c = q * 4 + u;
                        float2 th = sthf[c];
                        bool bit = (th.y > 0.f) ? (vv[u] >= th.x) : (vv[u] <= th.x);
                        bits |= (u64)bit << c;
                    }
                }
                sU[t] = bits;
            }
        } else {
            const short* src = (const short*)inprev;
            for (int t = threadIdx.x; t < nw; t += 256) {
                int w = t % CW;
                int x = (t / CW) % HIN;
                int yr = t / (HIN * CW);
                int y = ylo + yr;
                const int4* p = (const int4*)(src + (size_t)((n * HIN + y) * HIN + x) * Ci + w * 64);
                u64 bits = 0;
#pragma unroll
                for (int q = 0; q < 8; ++q) {
                    int4 v = p[q];
                    int wd[4] = {v.x, v.y, v.z, v.w};
#pragma unroll
                    for (int u = 0; u < 4; ++u) {
#pragma unroll
                        for (int h = 0; h < 2; ++h) {
                            int j = q * 8 + u * 2 + h;
                            int val = (int)(short)((h == 0) ? (wd[u] & 0xffff)
                                                            : ((unsigned)wd[u] >> 16));
                            int2 th = sthr[w * 65 + j];
                            bool bit = th.y ? (val <= th.x) : (val >= th.x);
                            bits |= (u64)bit << j;
                        }
                    }
                }
                sU[t] = bits;
            }
        }
        __syncthreads();

        const int lane = threadIdx.x & 63;
        const int wave = threadIdx.x >> 6;
        const int co = by * 64 + lane;
        const int yp = yp0 + wave;
        const int grow = n * HP + yp;
        const int y0 = (POOL ? 2 * yp : yp) - 1;
        int yoff[WS];
        bool ry[WS];
#pragma unroll
        for (int r = 0; r < WS; ++r) {
            int y = y0 + r;
            ry[r] = (unsigned)y < (unsigned)HIN;
            int yc = iclamp(y, 0, HIN - 1);
            yoff[r] = (yc - ylo) * (HIN * CW);
        }
        int cnt[HP * NA];
#pragma unroll
        for (int i = 0; i < HP * NA; ++i) cnt[i] = 0;

        if (yp > 0 && yp < HP - 1)
            row_accum<CW, HIN, POOL, WC, true>(sU, wpkT, Co, co, yoff, ry, cnt);
        else
            row_accum<CW, HIN, POOL, WC, false>(sU, wpkT, Co, co, yoff, ry, cnt);

        const int nr0 = (int)ry[0] + (int)ry[1] + (int)ry[2];
        const int nr1 = POOL ? ((int)ry[1] + (int)ry[2] + (int)ry[WS - 1]) : 0;

        int s1 = 0;
        long long s2 = 0;
        short* orow = out + (size_t)grow * HP * Co + co;
#pragma unroll
        for (int xp = 0; xp < HP; ++xp) {
            int ival;
            if constexpr (POOL) {
                int best = -2147483647;
#pragma unroll
                for (int py = 0; py < 2; ++py) {
                    const int nrv = py ? nr1 : nr0;
#pragma unroll
                    for (int qx = 0; qx < 2; ++qx) {
                        int ncols = 3;
                        if (xp == 0 && qx == 0) ncols = 2;
                        if (xp == HP - 1 && qx == 1) ncols = 2;
                        int v = 64 * CW * nrv * ncols - 2 * cnt[xp * NA + py * 2 + qx];
                        best = imax(best, v);
                    }
                }
                ival = best;
            } else {
                const int ncols = (xp == 0 || xp == HIN - 1) ? 2 : 3;
                ival = 64 * CW * nr0 * ncols - 2 * cnt[xp];
            }
            orow[(size_t)xp * Co] = (short)ival;
            s1 += ival;
            s2 += (long long)ival * ival;
        }

        if (threadIdx.x < 128) sacc[threadIdx.x] = 0ULL;
        __syncthreads();
        atomicAdd(&sacc[lane], (u64)(long long)s1);
        atomicAdd(&sacc[64 + lane], (u64)s2);
        __syncthreads();
        u64* sh = iacc + (size_t)(bx & 7) * 1024;
        if (threadIdx.x < 64)
            atomicAdd(&sh[2 * (by * 64 + threadIdx.x)], sacc[threadIdx.x]);
        else if (threadIdx.x < 128)
            atomicAdd(&sh[2 * (by * 64 + threadIdx.x - 64) + 1], sacc[threadIdx.x]);
    }
}

template <int CW, int HIN, bool POOL>
__device__ void bconv_tiny_stage(const short* __restrict__ inprev, const u64* __restrict__ pacc,
                                 const float* pg, const float* pb, int pcount,
                                 const u64* __restrict__ wpkT, short* __restrict__ out,
                                 u64* __restrict__ iacc, int Co, char* smem) {
    constexpr int NPX = HIN * HIN;
    constexpr int HP = POOL ? HIN / 2 : HIN;
    constexpr int Ci = CW * 64;
    int2* sthr = (int2*)smem;
    u64* sU = (u64*)(smem + 4608);
    u64* sacc = (u64*)(smem + 8704);

    for (int i = threadIdx.x; i < Ci; i += 256) {
        long long S1 = 0, S2 = 0;
#pragma unroll
        for (int s = 0; s < 8; ++s) {
            S1 += (long long)pacc[s * 1024 + 2 * i];
            S2 += (long long)pacc[s * 1024 + 2 * i + 1];
        }
        sthr[(i >> 6) * 65 + (i & 63)] = thr_int(S1, S2, pg[i], pb[i], pcount);
    }

    for (int vb = blockIdx.x; vb < 512; vb += gridDim.x) {
        __syncthreads();
        const int bx = vb & 63;
        const int by = vb >> 6;
        const int nbase = bx * 4;
        for (int t = threadIdx.x; t < 4 * NPX * CW; t += 256) {
            int img = t / (NPX * CW);
            int rem = t % (NPX * CW);
            int w = rem % CW;
            int i = rem / CW;
            const int4* p = (const int4*)(inprev + (size_t)((nbase + img) * NPX + i) * Ci + w * 64);
            u64 bits = 0;
#pragma unroll
            for (int q = 0; q < 8; ++q) {
                int4 v = p[q];
                int wd[4] = {v.x, v.y, v.z, v.w};
#pragma unroll
                for (int u = 0; u < 4; ++u) {
#pragma unroll
                    for (int h = 0; h < 2; ++h) {
                        int j = q * 8 + u * 2 + h;
                        int val = (int)(short)((h == 0) ? (wd[u] & 0xffff) : ((unsigned)wd[u] >> 16));
                        int2 th = sthr[w * 65 + j];
                        bool bit = th.y ? (val <= th.x) : (val >= th.x);
                        bits |= (u64)bit << j;
                    }
                }
            }
            sU[(size_t)img * (NPX * CW) + i * CW + w] = bits;
        }
        __syncthreads();

        const int lane = threadIdx.x & 63;
        const int co = by * 64 + lane;
        const int n = nbase + (threadIdx.x >> 6);
        const u64* inb = sU + (size_t)(threadIdx.x >> 6) * (NPX * CW);
        int cnt[NPX];
#pragma unroll
        for (int i = 0; i < NPX; ++i) cnt[i] = 0;

#pragma unroll 2
        for (int w = 0; w < CW; ++w) {
            u64 win[NPX];
#pragma unroll
            for (int i = 0; i < NPX; ++i) win[i] = inb[i * CW + w];
#pragma unroll
            for (int k = 0; k < 9; ++k) {
                u64 wb = wpkT[(size_t)(k * CW + w) * Co + co];
                const int ky = k / 3, kx = k % 3;
#pragma unroll
                for (int py = 0; py < HIN; ++py)
#pragma unroll
                    for (int px = 0; px < HIN; ++px) {
                        const int yy = py + ky - 1, xx = px + kx - 1;
                        if (yy >= 0 && yy < HIN && xx >= 0 && xx < HIN)
                            cnt[py * HIN + px] += (int)__popcll(win[yy * HIN + xx] ^ wb);
                    }
            }
        }

        int fin[NPX];
#pragma unroll
        for (int py = 0; py < HIN; ++py)
#pragma unroll
            for (int px = 0; px < HIN; ++px) {
                const int nk = ((py == 0 || py == HIN - 1) ? 2 : 3) *
                               ((px == 0 || px == HIN - 1) ? 2 : 3);
                fin[py * HIN + px] = 64 * CW * nk - 2 * cnt[py * HIN + px];
            }

        short vals[HP * HP];
        if constexpr (POOL) {
#pragma unroll
            for (int py = 0; py < HP; ++py)
#pragma unroll
                for (int px = 0; px < HP; ++px)
                    vals[py * HP + px] = (short)imax(
                        imax(fin[(2 * py) * HIN + 2 * px], fin[(2 * py) * HIN + 2 * px + 1]),
                        imax(fin[(2 * py + 1) * HIN + 2 * px],
                             fin[(2 * py + 1) * HIN + 2 * px + 1]));
        } else {
#pragma unroll
            for (int i = 0; i < NPX; ++i) vals[i] = (short)fin[i];
        }
#pragma unroll
        for (int p = 0; p < HP * HP; ++p) out[(size_t)(n * HP * HP + p) * Co + co] = vals[p];

        long long s1 = 0, s2 = 0;
#pragma unroll
        for (int p = 0; p < HP * HP; ++p) {
            s1 += vals[p];
            s2 += (long long)vals[p] * vals[p];
        }
        if (threadIdx.x < 128) sacc[threadIdx.x] = 0ULL;
        __syncthreads();
        atomicAdd(&sacc[lane], (u64)s1);
        atomicAdd(&sacc[64 + lane], (u64)s2);
        __syncthreads();
        u64* sh = iacc + (size_t)(bx & 7) * 1024;
        if (threadIdx.x < 64)
            atomicAdd(&sh[2 * (by * 64 + threadIdx.x)], sacc[threadIdx.x]);
        else if (threadIdx.x < 128)
            atomicAdd(&sh[2 * (by * 64 + threadIdx.x - 64) + 1], sacc[threadIdx.x]);
    }
}

__device__ void lin_stage(const u64* __restrict__ hp, const u64* __restrict__ wp,
                          const float* lb, const float* g, const float* bta,
                          u64* __restrict__ op, char* smem) {
    double* sh1 = (double*)smem;
    double* sh2 = (double*)(smem + 2048);
    float* smf = (float*)(smem + 4096);
    const int n = threadIdx.x;
    for (int o = blockIdx.x; o < 512; o += gridDim.x) {
        __syncthreads();
        const u64* hr = hp + n * 8;
        const u64* wr = wp + o * 8;
        int s = 0;
#pragma unroll
        for (int w = 0; w < 8; ++w) s += (int)__popcll(hr[w] ^ wr[w]);
        float val = (float)(512 - 2 * s) + lb[o];
        sh1[n] = (double)val;
        sh2[n] = (double)val * (double)val;
        __syncthreads();
        for (int st = 128; st > 0; st >>= 1) {
            if (n < st) {
                sh1[n] += sh1[n + st];
                sh2[n] += sh2[n + st];
            }
            __syncthreads();
        }
        if (n == 0) {
            double m = sh1[0] / 256.0;
            double var = sh2[0] / 256.0 - m * m;
            smf[0] = (float)m;
            smf[1] = (float)(1.0 / sqrt(var + EPSV));
        }
        __syncthreads();
        float zz = g[o] * (val - smf[0]) * smf[1] + bta[o];
        if (zz >= 0.f) atomicOr(&op[(size_t)n * 8 + (o >> 6)], 1ULL << (o & 63));
    }
}

__global__ __launch_bounds__(256, 2) void mega_kernel(MegaArgs A) {
    cg::grid_group gg = cg::this_grid();
    __shared__ __align__(16) char smem[18432];
    const int lane = threadIdx.x & 63;
    const int wave = threadIdx.x >> 6;

    // ---- S0: weight packing + zero stats/fc buffers ----
    for (int vb = blockIdx.x; vb < A.prow[10]; vb += gridDim.x) {
        __syncthreads();
        int z = vb * 19 + threadIdx.x;
        if (threadIdx.x < 19 && z < A.naccs) A.accs[z] = 0ULL;
        int l = 0;
        while (l < 9 && vb >= A.prow[l + 1]) ++l;
        const int row = vb - A.prow[l];
        const int CW = A.pCW[l];
        const int taps = A.ptaps[l];
        const int nf = CW * 64 * taps;
        float* buf = (float*)smem;
        const float* srow = A.psrc[l] + (size_t)row * nf;
        for (int i = threadIdx.x; i < nf; i += 256) buf[i] = srow[i];
        __syncthreads();
        const int t = threadIdx.x;
        if (t < taps * CW) {
            u64 bits = 0;
            if (taps == 9) {
                int k = t % 9, w = t / 9;
                for (int j = 0; j < 64; ++j) bits |= (u64)(buf[(w * 64 + j) * 9 + k] >= 0.f) << j;
                A.pdst[l][(size_t)(k * CW + w) * A.pCo[l] + row] = bits;
            } else {
                for (int j = 0; j < 64; ++j) bits |= (u64)(buf[t * 64 + j] >= 0.f) << j;
                A.pdst[l][(size_t)row * CW + t] = bits;
            }
        }
    }
    gg.sync();

    // ---- S1: conv0 ----
    {
        float ws[27];
#pragma unroll
        for (int j = 0; j < 27; ++j) ws[j] = (A.cw0[lane * 27 + j] >= 0.f) ? 1.f : -1.f;
        float* simg = (float*)smem;
        double* sh1 = (double*)(smem + 4096);
        double* sh2 = (double*)(smem + 6144);
        double* dacc0 = (double*)A.accs;
        for (int vb = blockIdx.x; vb < 2048; vb += gridDim.x) {
            __syncthreads();
            const int gp0 = vb * 32;
            const int n = gp0 >> 8;
            const int ypA = (gp0 >> 4) & 15;
            const int yb = 2 * ypA - 1;
            const float* xb = A.x + (size_t)n * 3072;
            for (int t = threadIdx.x; t < 612; t += 256) {
                int ci = t / 204;
                int rem = t % 204;
                int r = rem / 34;
                int ccv = rem % 34;
                int yy = yb + r;
                int xx = ccv - 1;
                float v = 0.f;
                if ((unsigned)yy < 32u && (unsigned)xx < 32u) v = xb[(ci * 32 + yy) * 32 + xx];
                simg[(ci * 6 + r) * 34 + ccv] = v;
            }
            __syncthreads();
            double s1 = 0.0, s2 = 0.0;
#pragma unroll 2
            for (int pi = 0; pi < 8; ++pi) {
                const int lp = wave * 8 + pi;
                const int gp = gp0 + lp;
                const int xp = lp & 15;
                const int rbase = 2 * (lp >> 4);
                const int cbase = 2 * xp;
                float win[3][4][4];
#pragma unroll
                for (int ci = 0; ci < 3; ++ci)
#pragma unroll
                    for (int r = 0; r < 4; ++r)
#pragma unroll
                        for (int c = 0; c < 4; ++c)
                            win[ci][r][c] = simg[(ci * 6 + rbase + r) * 34 + cbase + c];
                float a00 = 0.f, a01 = 0.f, a10 = 0.f, a11 = 0.f;
#pragma unroll
                for (int ci = 0; ci < 3; ++ci)
#pragma unroll
                    for (int ky = 0; ky < 3; ++ky)
#pragma unroll
                        for (int kx = 0; kx < 3; ++kx) {
                            float wv = ws[ci * 9 + ky * 3 + kx];
                            a00 += win[ci][ky][kx] * wv;
                            a01 += win[ci][ky][kx + 1] * wv;
                            a10 += win[ci][ky + 1][kx] * wv;
                            a11 += win[ci][ky + 1][kx + 1] * wv;
                        }
                float val = fmaxf(fmaxf(a00, a01), fmaxf(a10, a11));
                A.out0[(size_t)gp * 64 + lane] = val;
                s1 += (double)val;
                s2 += (double)val * (double)val;
            }
            sh1[wave * 64 + lane] = s1;
            sh2[wave * 64 + lane] = s2;
            __syncthreads();
            if (threadIdx.x < 64) {
                double t1 = 0.0, t2 = 0.0;
#pragma unroll
                for (int r = 0; r < 4; ++r) {
                    t1 += sh1[r * 64 + threadIdx.x];
                    t2 += sh2[r * 64 + threadIdx.x];
                }
                double* sh = dacc0 + (size_t)(vb & 7) * 1024;
                atomicAdd(&sh[2 * threadIdx.x], t1);
                atomicAdd(&sh[2 * threadIdx.x + 1], t2);
            }
        }
    }
    gg.sync();

    u64* iacc1 = A.accs + 1 * 8192;
    u64* iacc2 = A.accs + 2 * 8192;
    u64* iacc3 = A.accs + 3 * 8192;
    u64* iacc4 = A.accs + 4 * 8192;
    u64* iacc5 = A.accs + 5 * 8192;
    u64* iacc6 = A.accs + 6 * 8192;
    u64* iacc7 = A.accs + 7 * 8192;

    bconv_row_stage<1, 16, true, 1, true, 512, 2>(A.out0, A.accs, A.cg[0], A.ct[0], 65536,
                                                  A.wpkT[1], A.i16A, iacc1, 128, smem);
    gg.sync();
    bconv_row_stage<2, 8, false, 2, false, 512, 4>(A.i16A, iacc1, A.cg[1], A.ct[1], 16384,
                                                   A.wpkT[2], A.i16B, iacc2, 256, smem);
    gg.sync();
    bconv_row_stage<4, 8, true, 2, false, 256, 4>(A.i16B, iacc2, A.cg[2], A.ct[2], 16384,
                                                  A.wpkT[3], A.i16A, iacc3, 256, smem);
    gg.sync();
    bconv_row_stage<4, 4, false, 2, false, 256, 8>(A.i16A, iacc3, A.cg[3], A.ct[3], 4096,
                                                   A.wpkT[4], A.i16B, iacc4, 512, smem);
    gg.sync();
    bconv_tiny_stage<8, 4, true>(A.i16B, iacc4, A.cg[4], A.ct[4], 4096, A.wpkT[5], A.i16A,
                                 iacc5, 512, smem);
    gg.sync();
    bconv_tiny_stage<8, 2, false>(A.i16A, iacc5, A.cg[5], A.ct[5], 1024, A.wpkT[6], A.i16B,
                                  iacc6, 512, smem);
    gg.sync();
    bconv_tiny_stage<8, 2, true>(A.i16B, iacc6, A.cg[6], A.ct[6], 1024, A.wpkT[7], A.i16A,
                                 iacc7, 512, smem);
    gg.sync();

    // ---- S9: pack L7 output (BN7) -> act7 ----
    {
        int2* sthr = (int2*)smem;
        for (int i = threadIdx.x; i < 512; i += 256) {
            long long S1 = 0, S2 = 0;
#pragma unroll
            for (int s = 0; s < 8; ++s) {
                S1 += (long long)iacc7[s * 1024 + 2 * i];
                S2 += (long long)iacc7[s * 1024 + 2 * i + 1];
            }
            sthr[(i >> 6) * 65 + (i & 63)] = thr_int(S1, S2, A.cg[7][i], A.ct[7][i], 256);
        }
        __syncthreads();
        for (int vb = blockIdx.x; vb < 32; vb += gridDim.x) {
            int tid = vb * 256 + threadIdx.x;
            int part = tid & 3;
            int word = tid >> 2;
            int w = word & 7;
            int pix = word >> 3;
            const int4* r4 = (const int4*)(A.i16A + (size_t)pix * 512 + (w << 6) + part * 16);
            u64 bits = 0;
#pragma unroll
            for (int q = 0; q < 2; ++q) {
                int4 v = r4[q];
                int wd[4] = {v.x, v.y, v.z, v.w};
#pragma unroll
                for (int u = 0; u < 4; ++u) {
#pragma unroll
                    for (int h = 0; h < 2; ++h) {
                        int c = part * 16 + q * 8 + u * 2 + h;
                        int val = (int)(short)((h == 0) ? (wd[u] & 0xffff) : ((unsigned)wd[u] >> 16));
                        int2 t = sthr[w * 65 + c];
                        bool bit = t.y ? (val <= t.x) : (val >= t.x);
                        bits |= (u64)bit << c;
                    }
                }
            }
            bits |= __shfl_xor(bits, 1);
            bits |= __shfl_xor(bits, 2);
            if (part == 0) A.act7[word] = bits;
        }
    }
    gg.sync();

    lin_stage(A.act7, A.wpl[0], A.lb[0], A.lg[0], A.lt[0], A.fcs0, smem);
    gg.sync();
    lin_stage(A.fcs0, A.wpl[1], A.lb[1], A.lg[1], A.lt[1], A.fcs1, smem);
    gg.sync();

    if (blockIdx.x == 0) {
        double* w1 = (double*)smem;
        double* w2 = (double*)(smem + 512);
        const int n = threadIdx.x;
        u64 h[8];
#pragma unroll
        for (int w = 0; w < 8; ++w) h[w] = A.fcs1[n * 8 + w];
        float v[10];
#pragma unroll
        for (int o = 0; o < 10; ++o) {
            int s = 0;
#pragma unroll
            for (int w = 0; w < 8; ++w) s += (int)__popcll(h[w] ^ A.wpl[2][o * 8 + w]);
            v[o] = (float)(512 - 2 * s) + A.lb[2][o];
        }
#pragma unroll
        for (int o = 0; o < 10; ++o) {
            double a = (double)v[o];
            double b = a * a;
#pragma unroll
            for (int off = 32; off > 0; off >>= 1) {
                a += __shfl_xor(a, off);
                b += __shfl_xor(b, off);
            }
            if (lane == 0) {
                w1[wave * 10 + o] = a;
                w2[wave * 10 + o] = b;
            }
        }
        __syncthreads();
        float z[10];
#pragma unroll
        for (int o = 0; o < 10; ++o) {
            double S1 = w1[0 * 10 + o] + w1[1 * 10 + o] + w1[2 * 10 + o] + w1[3 * 10 + o];
            double S2 = w2[0 * 10 + o] + w2[1 * 10 + o] + w2[2 * 10 + o] + w2[3 * 10 + o];
            double m = S1 / 256.0;
            double var = S2 / 256.0 - m * m;
            float sm = (float)m;
            float siv = (float)(1.0 / sqrt(var + EPSV));
            z[o] = A.lg[2][o] * (v[o] - sm) * siv + A.lt[2][o];
        }
        float mx = z[0];
#pragma unroll
        for (int o = 1; o < 10; ++o) mx = fmaxf(mx, z[o]);
        float se = 0.f;
#pragma unroll
        for (int o = 0; o < 10; ++o) se += expf(z[o] - mx);
        float ls = logf(se);
#pragma unroll
        for (int o = 0; o < 10; ++o) A.out[n * 10 + o] = z[o] - mx - ls;
    }
}

// #####################################################################################

extern "C" void kernel_launch(void* const* d_in, const int* in_sizes, int n_in, void* d_out,
                              int out_size, void* d_ws, size_t ws_size, hipStream_t stream) {
    (void)in_sizes; (void)n_in; (void)out_size; (void)ws_size;
    const float* x = (const float*)d_in[0];
    const float *cw[8], *cg[8], *ct[8];
    for (int i = 0; i < 8; ++i) {
        cw[i] = (const float*)d_in[1 + 4 * i];
        cg[i] = (const float*)d_in[3 + 4 * i];
        ct[i] = (const float*)d_in[4 + 4 * i];
    }
    const float *lw[3], *lb[3], *lg[3], *lt[3];
    for (int i = 0; i < 3; ++i) {
        lw[i] = (const float*)d_in[33 + 4 * i];
        lb[i] = (const float*)d_in[34 + 4 * i];
        lg[i] = (const float*)d_in[35 + 4 * i];
        lt[i] = (const float*)d_in[36 + 4 * i];
    }

    static const int CIs[8] = {3, 64, 128, 256, 256, 512, 512, 512};
    static const int COs[8] = {64, 128, 256, 256, 512, 512, 512, 512};

    char* ws = (char*)d_ws;
    size_t off = 0;
    auto alloc = [&](size_t bytes) -> void* {
        void* p = ws + off;
        off += (bytes + 255) & ~(size_t)255;
        return p;
    };

    u64* accs = (u64*)alloc((size_t)8 * 8 * 1024 * 8);
    u64* fcs0 = (u64*)alloc(2048 * 8);
    u64* fcs1 = (u64*)alloc(2048 * 8);
    double* dacc0 = (double*)accs;
    auto iacc = [&](int layer) { return accs + (size_t)layer * 8192; };

    u64* wpkT[8] = {};
    for (int i = 1; i < 8; ++i) wpkT[i] = (u64*)alloc((size_t)COs[i] * 9 * (CIs[i] / 64) * 8);
    u64* wpl[3];
    int LO[3] = {512, 512, 10};
    for (int i = 0; i < 3; ++i) wpl[i] = (u64*)alloc((size_t)LO[i] * 8 * 8);
    u64* act7 = (u64*)alloc((size_t)256 * 8 * 8);
    float* out0 = (float*)alloc((size_t)65536 * 64 * 4);
    short* i16A = (short*)alloc((size_t)16384 * 256 * 2);
    short* i16B = (short*)alloc((size_t)16384 * 256 * 2);

    // ---- shared prep metadata ----
    MegaArgs A;
    int rb = 0;
    for (int i = 1; i < 8; ++i) {
        int e = i - 1;
        A.psrc[e] = cw[i];
        A.pdst[e] = wpkT[i];
        A.pCW[e] = CIs[i] / 64;
        A.pCo[e] = COs[i];
        A.ptaps[e] = 9;
        A.prow[e] = rb;
        rb += COs[i];
    }
    for (int i = 0; i < 3; ++i) {
        int e = 7 + i;
        A.psrc[e] = lw[i];
        A.pdst[e] = wpl[i];
        A.pCW[e] = 8;
        A.pCo[e] = LO[i];
        A.ptaps[e] = 1;
        A.prow[e] = rb;
        rb += LO[i];
    }
    A.prow[10] = rb;  // 3722
    A.accs = accs;
    A.naccs = 8 * 8 * 1024 + 2048 + 2048;
    A.x = x;
    A.cw0 = cw[0];
    for (int i = 0; i < 8; ++i) {
        A.cg[i] = cg[i];
        A.ct[i] = ct[i];
    }
    A.wpkT[0] = nullptr;
    for (int i = 1; i < 8; ++i) A.wpkT[i] = wpkT[i];
    A.i16A = i16A;
    A.i16B = i16B;
    A.act7 = act7;
    for (int i = 0; i < 3; ++i) {
        A.wpl[i] = wpl[i];
        A.lb[i] = lb[i];
        A.lg[i] = lg[i];
        A.lt[i] = lt[i];
    }
    A.fcs0 = fcs0;
    A.fcs1 = fcs1;
    A.out = (float*)d_out;
    A.out0 = out0;

    // ---- try cooperative mega kernel (grid sized by occupancy query) ----
    static int coop_grid = -2;
    if (coop_grid == -2) {
        int occ = 0;
        hipError_t qe = hipOccupancyMaxActiveBlocksPerMultiprocessor(
            &occ, (const void*)mega_kernel, 256, 0);
        if (qe == hipSuccess && occ >= 1) {
            int g = occ * 256;
            coop_grid = g > 512 ? 512 : g;
        } else {
            coop_grid = 0;
        }
    }
    if (coop_grid >= 64) {
        void* kargs[] = {(void*)&A};
        hipError_t le = hipLaunchCooperativeKernel((void*)mega_kernel, dim3(coop_grid),
                                                   dim3(256), kargs, 0, stream);
        if (le == hipSuccess) return;
        coop_grid = 0;  // don't retry the coop path
    }

    // ---- fallback: proven round-3 multi-kernel pipeline ----
    PrepArgs pa;
    for (int e = 0; e < 10; ++e) {
        pa.src[e] = A.psrc[e];
        pa.dst[e] = A.pdst[e];
        pa.CW[e] = A.pCW[e];
        pa.Co[e] = A.pCo[e];
        pa.taps[e] = A.ptaps[e];
        pa.rowbase[e] = A.prow[e];
    }
    pa.rowbase[10] = A.prow[10];
    pa.accs = accs;
    pa.naccs = A.naccs;
    prep_kernel<<<rb, 256, 0, stream>>>(pa);

    conv0_lane<<<2048, 256, 0, stream>>>(x, cw[0], out0, dacc0);

    bconv_row_f<1, 16, true, 1, true><<<dim3(512, 2), 256, 0, stream>>>(
        out0, dacc0, cg[0], ct[0], 65536, wpkT[1], i16A, iacc(1), 128);
    bconv_row_f<2, 8, false, 2, false><<<dim3(512, 4), 256, 0, stream>>>(
        i16A, iacc(1), cg[1], ct[1], 16384, wpkT[2], i16B, iacc(2), 256);
    bconv_row_f<4, 8, true, 2, false><<<dim3(256, 4), 256, 0, stream>>>(
        i16B, iacc(2), cg[2], ct[2], 16384, wpkT[3], i16A, iacc(3), 256);
    bconv_row_f<4, 4, false, 2, false><<<dim3(256, 8), 256, 0, stream>>>(
        i16A, iacc(3), cg[3], ct[3], 4096, wpkT[4], i16B, iacc(4), 512);
    bconv_tiny_f<8, 4, true><<<dim3(64, 8), 256, 0, stream>>>(
        i16B, iacc(4), cg[4], ct[4], 4096, wpkT[5], i16A, iacc(5), 512);
    bconv_tiny_f<8, 2, false><<<dim3(64, 8), 256, 0, stream>>>(
        i16A, iacc(5), cg[5], ct[5], 1024, wpkT[6], i16B, iacc(6), 512);
    bconv_tiny_f<8, 2, true><<<dim3(64, 8), 256, 0, stream>>>(
        i16B, iacc(6), cg[6], ct[6], 1024, wpkT[7], i16A, iacc(7), 512);

    bnpack_i<<<32, 256, 0, stream>>>(i16A, iacc(7), cg[7], ct[7], act7, 512, 3, 256);

    lin_kernel<<<512, 256, 0, stream>>>(act7, wpl[0], lb[0], lg[0], lt[0], fcs0);
    lin_kernel<<<512, 256, 0, stream>>>(fcs0, wpl[1], lb[1], lg[1], lt[1], fcs1);
    lin2_lsm<<<1, 256, 0, stream>>>(fcs1, wpl[2], lb[2], lg[2], lt[2], (float*)d_out);
}

// Round 7
// 394.574 us; speedup vs baseline: 2.2641x; 2.2641x over previous
//
#include <hip/hip_runtime.h>
#include <hip/hip_bf16.h>

typedef unsigned long long u64;

#define EPSV 1e-5

__device__ __forceinline__ int imax(int a, int b) { return a > b ? a : b; }
__device__ __forceinline__ int iclamp(int v, int lo, int hi) { return v < lo ? lo : (v > hi ? hi : v); }

// ================= prep: pack binary weights (coalesced via LDS) + zero stats shards =================
struct PrepArgs {
    const float* src[10];  // conv1..7 (l=0..6), lin0..2 (l=7..9)
    u64* dst[10];          // conv: transposed [k*CW+w][Co]; lin: [o][8]
    int CW[10];
    int Co[10];
    int taps[10];          // 9 conv, 1 lin
    int rowbase[11];       // prefix over Co
    u64* accs;
    int naccs;
};

__global__ __launch_bounds__(256) void prep_kernel(PrepArgs a) {
    __shared__ float buf[4608];  // max Ci*9 = 512*9
    const int blk = blockIdx.x;
    int z = blk * 18 + threadIdx.x;
    if (threadIdx.x < 18 && z < a.naccs) a.accs[z] = 0ULL;

    int l = 0;
    while (l < 9 && blk >= a.rowbase[l + 1]) ++l;
    const int row = blk - a.rowbase[l];
    const int CW = a.CW[l];
    const int taps = a.taps[l];
    const int nf = CW * 64 * taps;
    const float* srow = a.src[l] + (size_t)row * nf;
    for (int i = threadIdx.x; i < nf; i += 256) buf[i] = srow[i];
    __syncthreads();
    const int t = threadIdx.x;
    if (t < taps * CW) {
        u64 bits = 0;
        if (taps == 9) {
            int k = t % 9, w = t / 9;
            for (int j = 0; j < 64; ++j) bits |= (u64)(buf[(w * 64 + j) * 9 + k] >= 0.f) << j;
            a.dst[l][(size_t)(k * CW + w) * a.Co[l] + row] = bits;
        } else {
            for (int j = 0; j < 64; ++j) bits |= (u64)(buf[t * 64 + j] >= 0.f) << j;
            a.dst[l][(size_t)row * CW + t] = bits;
        }
    }
}

// ================= conv0: lane=co, input band staged in LDS, fused sharded stats =================
__global__ __launch_bounds__(256) void conv0_lane(const float* __restrict__ x,
                                                  const float* __restrict__ wgt,
                                                  float* __restrict__ out,
                                                  double* __restrict__ dacc) {
    const int lane = threadIdx.x & 63;
    const int wave = threadIdx.x >> 6;
    float ws[27];
#pragma unroll
    for (int j = 0; j < 27; ++j) ws[j] = (wgt[lane * 27 + j] >= 0.f) ? 1.f : -1.f;

    const int gp0 = blockIdx.x * 32;
    const int n = gp0 >> 8;
    const int ypA = (gp0 >> 4) & 15;
    const int yb = 2 * ypA - 1;

    __shared__ float simg[3][6][34];
    const float* xb = x + (size_t)n * 3072;
    for (int t = threadIdx.x; t < 612; t += 256) {
        int ci = t / 204;
        int rem = t % 204;
        int r = rem / 34;
        int cc = rem % 34;
        int yy = yb + r;
        int xx = cc - 1;
        float v = 0.f;
        if ((unsigned)yy < 32u && (unsigned)xx < 32u) v = xb[(ci * 32 + yy) * 32 + xx];
        simg[ci][r][cc] = v;
    }
    __syncthreads();

    double s1 = 0.0, s2 = 0.0;
#pragma unroll 2
    for (int pi = 0; pi < 8; ++pi) {
        const int lp = wave * 8 + pi;
        const int gp = gp0 + lp;
        const int xp = lp & 15;
        const int rbase = 2 * (lp >> 4);
        const int cbase = 2 * xp;
        float win[3][4][4];
#pragma unroll
        for (int ci = 0; ci < 3; ++ci)
#pragma unroll
            for (int r = 0; r < 4; ++r)
#pragma unroll
                for (int c = 0; c < 4; ++c) win[ci][r][c] = simg[ci][rbase + r][cbase + c];
        float a00 = 0.f, a01 = 0.f, a10 = 0.f, a11 = 0.f;
#pragma unroll
        for (int ci = 0; ci < 3; ++ci)
#pragma unroll
            for (int ky = 0; ky < 3; ++ky)
#pragma unroll
                for (int kx = 0; kx < 3; ++kx) {
                    float wv = ws[ci * 9 + ky * 3 + kx];
                    a00 += win[ci][ky][kx] * wv;
                    a01 += win[ci][ky][kx + 1] * wv;
                    a10 += win[ci][ky + 1][kx] * wv;
                    a11 += win[ci][ky + 1][kx + 1] * wv;
                }
        float val = fmaxf(fmaxf(a00, a01), fmaxf(a10, a11));
        out[(size_t)gp * 64 + lane] = val;
        s1 += (double)val;
        s2 += (double)val * (double)val;
    }
    __shared__ double sh1[4][64], sh2[4][64];
    sh1[wave][lane] = s1;
    sh2[wave][lane] = s2;
    __syncthreads();
    if (threadIdx.x < 64) {
        double t1 = 0.0, t2 = 0.0;
#pragma unroll
        for (int r = 0; r < 4; ++r) { t1 += sh1[r][threadIdx.x]; t2 += sh2[r][threadIdx.x]; }
        double* sh = dacc + (size_t)(blockIdx.x & 7) * 1024;
        atomicAdd(&sh[2 * threadIdx.x], t1);
        atomicAdd(&sh[2 * threadIdx.x + 1], t2);
    }
}

// ================= bnpack float (layer 0), 4-way word split, fused thresholds =================
// 4 threads per output word: each reads 16 floats (64 B), shuffle-OR combine.
__global__ __launch_bounds__(256) void bnpack_f(const float* __restrict__ in,
                                                const double* __restrict__ dacc,
                                                const float* __restrict__ g,
                                                const float* __restrict__ b,
                                                u64* __restrict__ act, int count) {
    __shared__ float2 sthr[64];
    if (threadIdx.x < 64) {
        int i = threadIdx.x;
        double S1 = 0.0, S2 = 0.0;
#pragma unroll
        for (int s = 0; s < 8; ++s) {
            S1 += dacc[s * 1024 + 2 * i];
            S2 += dacc[s * 1024 + 2 * i + 1];
        }
        double m = S1 / count;
        double var = S2 / count - m * m;
        double sc = (double)g[i] / sqrt(var + EPSV);
        float2 r;
        if (sc == 0.0) r = make_float2(b[i] >= 0.f ? -3.0e38f : 3.0e38f, 1.f);
        else {
            double t = m - (double)b[i] / sc;
            r = make_float2((float)t, sc > 0.0 ? 1.f : -1.f);
        }
        sthr[i] = r;
    }
    __syncthreads();
    int tid = blockIdx.x * 256 + threadIdx.x;
    int part = tid & 3;
    int word = tid >> 2;
    const float4* r4 = (const float4*)(in + (size_t)word * 64 + part * 16);
    u64 bits = 0;
#pragma unroll
    for (int q = 0; q < 4; ++q) {
        float4 v = r4[q];
        float vv[4] = {v.x, v.y, v.z, v.w};
#pragma unroll
        for (int u = 0; u < 4; ++u) {
            int c = part * 16 + q * 4 + u;
            float2 t = sthr[c];
            bool bit = (t.y > 0.f) ? (vv[u] >= t.x) : (vv[u] <= t.x);
            bits |= (u64)bit << c;
        }
    }
    bits |= __shfl_xor(bits, 1);
    bits |= __shfl_xor(bits, 2);
    if (part == 0) act[word] = bits;
}

// ================= bnpack int16, 4-way word split, padded threshold table =================
__global__ __launch_bounds__(256) void bnpack_i(const short* __restrict__ in,
                                                const u64* __restrict__ iacc,
                                                const float* __restrict__ g,
                                                const float* __restrict__ b,
                                                u64* __restrict__ act, int Co, int wshift,
                                                int count) {
    __shared__ int2 sthr[520];  // stride 65 breaks the 8-way bank conflict
    for (int i = threadIdx.x; i < Co; i += 256) {
        long long S1 = 0, S2 = 0;
#pragma unroll
        for (int s = 0; s < 8; ++s) {
            S1 += (long long)iacc[s * 1024 + 2 * i];
            S2 += (long long)iacc[s * 1024 + 2 * i + 1];
        }
        double m = (double)S1 / count;
        double var = (double)S2 / count - m * m;
        double sc = (double)g[i] / sqrt(var + EPSV);
        int2 r;
        if (sc == 0.0) r = make_int2(b[i] >= 0.f ? (int)0x80000000 : 0x7fffffff, 0);
        else {
            double t = m - (double)b[i] / sc;
            if (t > 1.0e9) t = 1.0e9;
            if (t < -1.0e9) t = -1.0e9;
            r = (sc > 0.0) ? make_int2((int)ceil(t), 0) : make_int2((int)floor(t), 1);
        }
        sthr[(i >> 6) * 65 + (i & 63)] = r;
    }
    __syncthreads();
    int tid = blockIdx.x * 256 + threadIdx.x;
    int part = tid & 3;
    int word = tid >> 2;
    int w = word & ((1 << wshift) - 1);
    int pix = word >> wshift;
    const int4* r4 = (const int4*)(in + (size_t)pix * Co + (w << 6) + part * 16);
    u64 bits = 0;
#pragma unroll
    for (int q = 0; q < 2; ++q) {
        int4 v = r4[q];
        int words4[4] = {v.x, v.y, v.z, v.w};
#pragma unroll
        for (int u = 0; u < 4; ++u) {
#pragma unroll
            for (int h = 0; h < 2; ++h) {
                int c = part * 16 + q * 8 + u * 2 + h;
                int val = (int)(short)((h == 0) ? (words4[u] & 0xffff) : ((unsigned)words4[u] >> 16));
                int2 t = sthr[w * 65 + c];
                bool bit = t.y ? (val <= t.x) : (val >= t.x);
                bits |= (u64)bit << c;
            }
        }
    }
    bits |= __shfl_xor(bits, 1);
    bits |= __shfl_xor(bits, 2);
    if (part == 0) act[word] = bits;
}

// ================= row-sliding binary conv, lane=co (layers 1..4) =================
// Wave = one output row (HP px); weights amortized over the row; sliding window
// registers. All array indices compile-time literals (dynamic index => scratch
// spill). INTERIOR: no per-tap selects (wave-uniform split).
template <int CW, int HIN, bool POOL, int WC, bool INTERIOR>
__device__ __forceinline__ void row_accum(const u64* __restrict__ inb,
                                          const u64* __restrict__ wpkT, int Co, int co,
                                          const int* yoff, const bool* ry, int* acc) {
    constexpr int HP = POOL ? HIN / 2 : HIN;
    constexpr int WS = POOL ? 4 : 3;
    constexpr int NA = POOL ? 4 : 1;
#pragma unroll 1
    for (int w0 = 0; w0 < CW; w0 += WC) {
        u64 wg[9 * WC];
#pragma unroll
        for (int k = 0; k < 9; ++k)
#pragma unroll
            for (int w = 0; w < WC; ++w)
                wg[k * WC + w] = wpkT[(size_t)(k * CW + w0 + w) * Co + co];
        u64 cur[WS][WS][WC];
#pragma unroll
        for (int d = 0; d < WS; ++d) {
            int cc = d - 1;
            int ccc = cc < 0 ? 0 : cc;
#pragma unroll
            for (int r = 0; r < WS; ++r) {
                const u64* p = inb + yoff[r] + ccc * CW + w0;
                if (WC == 1) {
                    cur[r][d][0] = p[0];
                } else {
                    ulonglong2 v = *(const ulonglong2*)p;
                    cur[r][d][0] = v.x;
                    cur[r][d][1] = v.y;
                }
            }
        }
#pragma unroll
        for (int xp = 0; xp < HP; ++xp) {
            if constexpr (POOL) {
#pragma unroll
                for (int py = 0; py < 2; ++py)
#pragma unroll
                    for (int qx = 0; qx < 2; ++qx)
#pragma unroll
                        for (int ky = 0; ky < 3; ++ky)
#pragma unroll
                            for (int kx = 0; kx < 3; ++kx) {
                                int d = qx + kx;
                                int cc = 2 * xp + d - 1;
                                if (cc >= 0 && cc < HIN) {  // folds (xp,d literal)
#pragma unroll
                                    for (int w = 0; w < WC; ++w) {
                                        int pcv = 64 - 2 * (int)__popcll(cur[py + ky][d][w] ^
                                                                         wg[(ky * 3 + kx) * WC + w]);
                                        if constexpr (INTERIOR)
                                            acc[xp * NA + py * 2 + qx] += pcv;
                                        else
                                            acc[xp * NA + py * 2 + qx] += ry[py + ky] ? pcv : 0;
                                    }
                                }
                            }
            } else {
#pragma unroll
                for (int ky = 0; ky < 3; ++ky)
#pragma unroll
                    for (int kx = 0; kx < 3; ++kx) {
                        int cc = xp + kx - 1;
                        if (cc >= 0 && cc < HIN) {
#pragma unroll
                            for (int w = 0; w < WC; ++w) {
                                int pcv = 64 - 2 * (int)__popcll(cur[ky][kx][w] ^
                                                                 wg[(ky * 3 + kx) * WC + w]);
                                if constexpr (INTERIOR)
                                    acc[xp] += pcv;
                                else
                                    acc[xp] += ry[ky] ? pcv : 0;
                            }
                        }
                    }
            }
            if (xp < HP - 1) {
                if constexpr (POOL) {
#pragma unroll
                    for (int r = 0; r < WS; ++r)
#pragma unroll
                        for (int w = 0; w < WC; ++w) {
                            cur[r][0][w] = cur[r][2][w];
                            cur[r][1][w] = cur[r][3][w];
                        }
#pragma unroll
                    for (int dd = 2; dd < 4; ++dd) {
                        int cc = 2 * (xp + 1) + dd - 1;
                        int ccc = cc >= HIN ? HIN - 1 : cc;
#pragma unroll
                        for (int r = 0; r < WS; ++r) {
                            const u64* p = inb + yoff[r] + ccc * CW + w0;
                            if (WC == 1) {
                                cur[r][dd][0] = p[0];
                            } else {
                                ulonglong2 v = *(const ulonglong2*)p;
                                cur[r][dd][0] = v.x;
                                cur[r][dd][1] = v.y;
                            }
                        }
                    }
                } else {
#pragma unroll
                    for (int r = 0; r < WS; ++r)
#pragma unroll
                        for (int w = 0; w < WC; ++w) {
                            cur[r][0][w] = cur[r][1][w];
                            cur[r][1][w] = cur[r][2][w];
                        }
                    int cc = xp + 2;
                    int ccc = cc >= HIN ? HIN - 1 : cc;
#pragma unroll
                    for (int r = 0; r < WS; ++r) {
                        const u64* p = inb + yoff[r] + ccc * CW + w0;
                        if (WC == 1) {
                            cur[r][2][0] = p[0];
                        } else {
                            ulonglong2 v = *(const ulonglong2*)p;
                            cur[r][2][0] = v.x;
                            cur[r][2][1] = v.y;
                        }
                    }
                }
            }
        }
    }
}

template <int CW, int HIN, bool POOL, int WC>
__global__ __launch_bounds__(256) void bconv_row(const u64* __restrict__ in,
                                                 const u64* __restrict__ wpkT,
                                                 short* __restrict__ out,
                                                 u64* __restrict__ iacc, int Co) {
    constexpr int HP = POOL ? HIN / 2 : HIN;
    constexpr int WS = POOL ? 4 : 3;
    constexpr int NA = POOL ? 4 : 1;
    const int lane = threadIdx.x & 63;
    const int co = blockIdx.y * 64 + lane;
    const int grow = blockIdx.x * 4 + (threadIdx.x >> 6);  // n*HP + yp
    const int n = grow / HP;
    const int yp = grow % HP;
    const int y0 = (POOL ? 2 * yp : yp) - 1;
    const u64* inb = in + (size_t)n * (HIN * HIN * CW);
    int yoff[WS];
    bool ry[WS];
#pragma unroll
    for (int r = 0; r < WS; ++r) {
        int y = y0 + r;
        ry[r] = (unsigned)y < (unsigned)HIN;
        int yc = iclamp(y, 0, HIN - 1);
        yoff[r] = yc * HIN * CW;
    }
    int acc[HP * NA];
#pragma unroll
    for (int i = 0; i < HP * NA; ++i) acc[i] = 0;

    if (yp > 0 && yp < HP - 1)
        row_accum<CW, HIN, POOL, WC, true>(inb, wpkT, Co, co, yoff, ry, acc);
    else
        row_accum<CW, HIN, POOL, WC, false>(inb, wpkT, Co, co, yoff, ry, acc);

    int s1 = 0;
    long long s2 = 0;
    short* orow = out + (size_t)grow * HP * Co + co;
#pragma unroll
    for (int xp = 0; xp < HP; ++xp) {
        int ival;
        if constexpr (POOL)
            ival = imax(imax(acc[xp * 4], acc[xp * 4 + 1]), imax(acc[xp * 4 + 2], acc[xp * 4 + 3]));
        else
            ival = acc[xp];
        orow[(size_t)xp * Co] = (short)ival;
        s1 += ival;
        s2 += (long long)ival * ival;
    }

    __shared__ u64 sacc[128];
    if (threadIdx.x < 128) sacc[threadIdx.x] = 0ULL;
    __syncthreads();
    atomicAdd(&sacc[lane], (u64)(long long)s1);
    atomicAdd(&sacc[64 + lane], (u64)s2);
    __syncthreads();
    u64* sh = iacc + (size_t)(blockIdx.x & 7) * 1024;
    if (threadIdx.x < 64)
        atomicAdd(&sh[2 * (blockIdx.y * 64 + threadIdx.x)], sacc[threadIdx.x]);
    else if (threadIdx.x < 128)
        atomicAdd(&sh[2 * (blockIdx.y * 64 + threadIdx.x - 64) + 1], sacc[threadIdx.x]);
}

// ================= binary conv for tiny images (layers 5..7, HIN in {2,4}) =================
template <int CW, int HIN, bool POOL>
__global__ __launch_bounds__(256) void bconv_tiny(const u64* __restrict__ in,
                                                  const u64* __restrict__ wpkT,
                                                  short* __restrict__ out,
                                                  u64* __restrict__ iacc, int Co) {
    constexpr int NPX = HIN * HIN;
    constexpr int HP = POOL ? HIN / 2 : HIN;
    const int lane = threadIdx.x & 63;
    const int co = blockIdx.y * 64 + lane;
    const int n = blockIdx.x * 4 + (threadIdx.x >> 6);
    const u64* inb = in + (size_t)n * CW * NPX;
    int acc[NPX];
#pragma unroll
    for (int i = 0; i < NPX; ++i) acc[i] = 0;

#pragma unroll 2
    for (int w = 0; w < CW; ++w) {
        u64 win[NPX];
#pragma unroll
        for (int i = 0; i < NPX; ++i) win[i] = inb[i * CW + w];
#pragma unroll
        for (int k = 0; k < 9; ++k) {
            u64 wb = wpkT[(size_t)(k * CW + w) * Co + co];
            const int ky = k / 3, kx = k % 3;
#pragma unroll
            for (int py = 0; py < HIN; ++py)
#pragma unroll
                for (int px = 0; px < HIN; ++px) {
                    const int yy = py + ky - 1, xx = px + kx - 1;
                    if (yy >= 0 && yy < HIN && xx >= 0 && xx < HIN)
                        acc[py * HIN + px] += 64 - 2 * (int)__popcll(win[yy * HIN + xx] ^ wb);
                }
        }
    }

    short vals[HP * HP];
    if constexpr (POOL) {
#pragma unroll
        for (int py = 0; py < HP; ++py)
#pragma unroll
            for (int px = 0; px < HP; ++px)
                vals[py * HP + px] = (short)imax(
                    imax(acc[(2 * py) * HIN + 2 * px], acc[(2 * py) * HIN + 2 * px + 1]),
                    imax(acc[(2 * py + 1) * HIN + 2 * px], acc[(2 * py + 1) * HIN + 2 * px + 1]));
    } else {
#pragma unroll
        for (int i = 0; i < NPX; ++i) vals[i] = (short)acc[i];
    }
#pragma unroll
    for (int p = 0; p < HP * HP; ++p) out[(size_t)(n * HP * HP + p) * Co + co] = vals[p];

    long long s1 = 0, s2 = 0;
#pragma unroll
    for (int p = 0; p < HP * HP; ++p) {
        s1 += vals[p];
        s2 += (long long)vals[p] * vals[p];
    }
    __shared__ u64 sacc[128];
    if (threadIdx.x < 128) sacc[threadIdx.x] = 0ULL;
    __syncthreads();
    atomicAdd(&sacc[lane], (u64)s1);
    atomicAdd(&sacc[64 + lane], (u64)s2);
    __syncthreads();
    u64* sh = iacc + (size_t)(blockIdx.x & 7) * 1024;
    if (threadIdx.x < 64)
        atomicAdd(&sh[2 * (blockIdx.y * 64 + threadIdx.x)], sacc[threadIdx.x]);
    else if (threadIdx.x < 128)
        atomicAdd(&sh[2 * (blockIdx.y * 64 + threadIdx.x - 64) + 1], sacc[threadIdx.x]);
}

// ================= binarized linear + BN1 (+ hardtanh) =================
__global__ __launch_bounds__(256) void lin_kernel(const u64* __restrict__ hp,
                                                  const u64* __restrict__ wp,
                                                  const float* __restrict__ lb,
                                                  const float* __restrict__ g,
                                                  const float* __restrict__ bta,
                                                  float* __restrict__ z, int O, int applyHt) {
    int o = blockIdx.x;
    int n = threadIdx.x;
    const u64* hr = hp + n * 8;
    const u64* wr = wp + o * 8;
    int s = 0;
#pragma unroll
    for (int w = 0; w < 8; ++w) s += (int)__popcll(hr[w] ^ wr[w]);
    float val = (float)(512 - 2 * s) + lb[o];
    __shared__ double sh1[256], sh2[256];
    sh1[n] = (double)val;
    sh2[n] = (double)val * (double)val;
    __syncthreads();
    for (int st = 128; st > 0; st >>= 1) {
        if (n < st) {
            sh1[n] += sh1[n + st];
            sh2[n] += sh2[n + st];
        }
        __syncthreads();
    }
    __shared__ float sm, siv;
    if (n == 0) {
        double m = sh1[0] / 256.0;
        double var = sh2[0] / 256.0 - m * m;
        sm = (float)m;
        siv = (float)(1.0 / sqrt(var + EPSV));
    }
    __syncthreads();
    float zz = g[o] * (val - sm) * siv + bta[o];
    if (applyHt) zz = fminf(1.f, fmaxf(-1.f, zz));
    z[(size_t)n * O + o] = zz;
}

// pack post-ht FC activations [256,512] -> [256,8], 4-way word split
__global__ void pack_rows(const float* __restrict__ z, u64* __restrict__ hp) {
    int tid = blockIdx.x * 256 + threadIdx.x;  // 8192 total
    int part = tid & 3;
    int word = tid >> 2;
    int ww = word & 7;
    int n = word >> 3;
    const float4* r4 = (const float4*)(z + (size_t)n * 512 + (ww << 6) + part * 16);
    u64 bits = 0;
#pragma unroll
    for (int q = 0; q < 4; ++q) {
        float4 v = r4[q];
        float vv[4] = {v.x, v.y, v.z, v.w};
#pragma unroll
        for (int u = 0; u < 4; ++u) bits |= (u64)(vv[u] >= 0.f) << (part * 16 + q * 4 + u);
    }
    bits |= __shfl_xor(bits, 1);
    bits |= __shfl_xor(bits, 2);
    if (part == 0) hp[word] = bits;
}

__global__ void lsm_kernel(const float* __restrict__ z, float* __restrict__ out) {
    int n = blockIdx.x * 64 + threadIdx.x;
    if (n >= 256) return;
    float v[10];
    float m = -1e30f;
#pragma unroll
    for (int i = 0; i < 10; ++i) {
        v[i] = z[n * 10 + i];
        m = fmaxf(m, v[i]);
    }
    float s = 0.f;
#pragma unroll
    for (int i = 0; i < 10; ++i) s += expf(v[i] - m);
    float ls = logf(s);
#pragma unroll
    for (int i = 0; i < 10; ++i) out[n * 10 + i] = v[i] - m - ls;
}

extern "C" void kernel_launch(void* const* d_in, const int* in_sizes, int n_in, void* d_out,
                              int out_size, void* d_ws, size_t ws_size, hipStream_t stream) {
    (void)in_sizes; (void)n_in; (void)out_size; (void)ws_size;
    const float* x = (const float*)d_in[0];
    const float *cw[8], *cb[8], *cg[8], *ct[8];
    for (int i = 0; i < 8; ++i) {
        cw[i] = (const float*)d_in[1 + 4 * i];
        cb[i] = (const float*)d_in[2 + 4 * i];
        cg[i] = (const float*)d_in[3 + 4 * i];
        ct[i] = (const float*)d_in[4 + 4 * i];
    }
    const float *lw[3], *lb[3], *lg[3], *lt[3];
    for (int i = 0; i < 3; ++i) {
        lw[i] = (const float*)d_in[33 + 4 * i];
        lb[i] = (const float*)d_in[34 + 4 * i];
        lg[i] = (const float*)d_in[35 + 4 * i];
        lt[i] = (const float*)d_in[36 + 4 * i];
    }

    static const int CIs[8] = {3, 64, 128, 256, 256, 512, 512, 512};
    static const int COs[8] = {64, 128, 256, 256, 512, 512, 512, 512};
    static const int HPs[8] = {16, 8, 8, 4, 4, 2, 2, 1};

    char* ws = (char*)d_ws;
    size_t off = 0;
    auto alloc = [&](size_t bytes) -> void* {
        void* p = ws + off;
        off += (bytes + 255) & ~(size_t)255;
        return p;
    };

    u64* wpkT[8] = {};
    for (int i = 1; i < 8; ++i) wpkT[i] = (u64*)alloc((size_t)COs[i] * 9 * (CIs[i] / 64) * 8);
    u64* wpl[3];
    int LO[3] = {512, 512, 10};
    for (int i = 0; i < 3; ++i) wpl[i] = (u64*)alloc((size_t)LO[i] * 8 * 8);
    u64* act[8];
    for (int i = 0; i < 8; ++i) act[i] = (u64*)alloc((size_t)256 * (COs[i] / 64) * HPs[i] * HPs[i] * 8);
    u64* fcs0 = (u64*)alloc(2048 * 8);
    u64* fcs1 = (u64*)alloc(2048 * 8);
    float* out0 = (float*)alloc((size_t)65536 * 64 * 4);
    short* i16A = (short*)alloc((size_t)16384 * 256 * 2);
    short* i16B = (short*)alloc((size_t)16384 * 256 * 2);
    float* z0 = (float*)alloc((size_t)256 * 512 * 4);
    float* z1 = (float*)alloc((size_t)256 * 512 * 4);
    float* z2 = (float*)alloc((size_t)256 * 10 * 4);
    // sharded stats: 8 layers x 8 shards x 1024 u64 (layer0 = doubles)
    u64* accs = (u64*)alloc((size_t)8 * 8 * 1024 * 8);
    double* dacc0 = (double*)accs;
    auto iacc = [&](int layer) { return accs + (size_t)layer * 8192; };

    // ---- prep ----
    PrepArgs pa;
    int rb = 0;
    for (int i = 1; i < 8; ++i) {
        int e = i - 1;
        pa.src[e] = cw[i];
        pa.dst[e] = wpkT[i];
        pa.CW[e] = CIs[i] / 64;
        pa.Co[e] = COs[i];
        pa.taps[e] = 9;
        pa.rowbase[e] = rb;
        rb += COs[i];
    }
    for (int i = 0; i < 3; ++i) {
        int e = 7 + i;
        pa.src[e] = lw[i];
        pa.dst[e] = wpl[i];
        pa.CW[e] = 8;
        pa.Co[e] = LO[i];
        pa.taps[e] = 1;
        pa.rowbase[e] = rb;
        rb += LO[i];
    }
    pa.rowbase[10] = rb;  // 3722
    pa.accs = accs;
    pa.naccs = 8 * 8 * 1024;
    prep_kernel<<<rb, 256, 0, stream>>>(pa);

    // ---- L0 ----
    conv0_lane<<<2048, 256, 0, stream>>>(x, cw[0], out0, dacc0);
    bnpack_f<<<1024, 256, 0, stream>>>(out0, dacc0, cg[0], ct[0], act[0], 65536);

    // ---- L1: 64ch 16x16 -> 128ch, pool -> 8x8 ----
    bconv_row<1, 16, true, 1><<<dim3(512, 2), 256, 0, stream>>>(act[0], wpkT[1], i16A, iacc(1), 128);
    bnpack_i<<<512, 256, 0, stream>>>(i16A, iacc(1), cg[1], ct[1], act[1], 128, 1, 16384);

    // ---- L2: 128ch 8x8 -> 256ch ----
    bconv_row<2, 8, false, 2><<<dim3(512, 4), 256, 0, stream>>>(act[1], wpkT[2], i16B, iacc(2), 256);
    bnpack_i<<<1024, 256, 0, stream>>>(i16B, iacc(2), cg[2], ct[2], act[2], 256, 2, 16384);

    // ---- L3: 256ch 8x8 -> 256ch, pool -> 4x4 ----
    bconv_row<4, 8, true, 2><<<dim3(256, 4), 256, 0, stream>>>(act[2], wpkT[3], i16A, iacc(3), 256);
    bnpack_i<<<256, 256, 0, stream>>>(i16A, iacc(3), cg[3], ct[3], act[3], 256, 2, 4096);

    // ---- L4: 256ch 4x4 -> 512ch ----
    bconv_row<4, 4, false, 2><<<dim3(256, 8), 256, 0, stream>>>(act[3], wpkT[4], i16B, iacc(4), 512);
    bnpack_i<<<512, 256, 0, stream>>>(i16B, iacc(4), cg[4], ct[4], act[4], 512, 3, 4096);

    // ---- L5: 512ch 4x4 -> 512ch, pool -> 2x2 (tiny) ----
    bconv_tiny<8, 4, true><<<dim3(64, 8), 256, 0, stream>>>(act[4], wpkT[5], i16A, iacc(5), 512);
    bnpack_i<<<128, 256, 0, stream>>>(i16A, iacc(5), cg[5], ct[5], act[5], 512, 3, 1024);

    // ---- L6: 512ch 2x2 -> 512ch (tiny) ----
    bconv_tiny<8, 2, false><<<dim3(64, 8), 256, 0, stream>>>(act[5], wpkT[6], i16B, iacc(6), 512);
    bnpack_i<<<128, 256, 0, stream>>>(i16B, iacc(6), cg[6], ct[6], act[6], 512, 3, 1024);

    // ---- L7: 512ch 2x2 -> 512ch, pool -> 1x1 (tiny) ----
    bconv_tiny<8, 2, true><<<dim3(64, 8), 256, 0, stream>>>(act[6], wpkT[7], i16A, iacc(7), 512);
    bnpack_i<<<32, 256, 0, stream>>>(i16A, iacc(7), cg[7], ct[7], act[7], 512, 3, 256);

    // ---- FC ----
    lin_kernel<<<512, 256, 0, stream>>>(act[7], wpl[0], lb[0], lg[0], lt[0], z0, 512, 1);
    pack_rows<<<32, 256, 0, stream>>>(z0, fcs0);
    lin_kernel<<<512, 256, 0, stream>>>(fcs0, wpl[1], lb[1], lg[1], lt[1], z1, 512, 1);
    pack_rows<<<32, 256, 0, stream>>>(z1, fcs1);
    lin_kernel<<<10, 256, 0, stream>>>(fcs1, wpl[2], lb[2], lg[2], lt[2], z2, 10, 0);
    lsm_kernel<<<4, 64, 0, stream>>>(z2, (float*)d_out);
}

// Round 8
// 383.478 us; speedup vs baseline: 2.3296x; 1.0289x over previous
//
#include <hip/hip_runtime.h>
#include <hip/hip_bf16.h>

typedef unsigned long long u64;

#define EPSV 1e-5

__device__ __forceinline__ int imax(int a, int b) { return a > b ? a : b; }
__device__ __forceinline__ int iclamp(int v, int lo, int hi) { return v < lo ? lo : (v > hi ? hi : v); }

// ================= fused: prep (weight packing) + conv0, disjoint block ranges =================
// Blocks [0,2048): conv0 (fp32 conv, sign(W), pool, sharded stats -> dacc).
// Blocks [2048, 2048+rowtotal): weight packing (identical math to round-0 prep_kernel).
// accs zeroing moved to a hipMemsetAsync BEFORE this kernel (conv0 atomics race otherwise).
struct PrepArgs {
    const float* src[10];  // conv1..7 (l=0..6), lin0..2 (l=7..9)
    u64* dst[10];          // conv: transposed [k*CW+w][Co]; lin: [o][8]
    int CW[10];
    int Co[10];
    int taps[10];          // 9 conv, 1 lin
    int rowbase[11];       // prefix over Co
};

__global__ __launch_bounds__(256) void prep_conv0(PrepArgs a, const float* __restrict__ x,
                                                  const float* __restrict__ wgt,
                                                  float* __restrict__ out,
                                                  double* __restrict__ dacc) {
    __shared__ __align__(16) char smem[18432];
    if (blockIdx.x >= 2048) {
        // ---- prep path (verbatim round-0 math, minus accs zeroing) ----
        float* buf = (float*)smem;  // max Ci*9 = 4608 floats
        const int blk = blockIdx.x - 2048;
        int l = 0;
        while (l < 9 && blk >= a.rowbase[l + 1]) ++l;
        const int row = blk - a.rowbase[l];
        const int CW = a.CW[l];
        const int taps = a.taps[l];
        const int nf = CW * 64 * taps;
        const float* srow = a.src[l] + (size_t)row * nf;
        for (int i = threadIdx.x; i < nf; i += 256) buf[i] = srow[i];
        __syncthreads();
        const int t = threadIdx.x;
        if (t < taps * CW) {
            u64 bits = 0;
            if (taps == 9) {
                int k = t % 9, w = t / 9;
                for (int j = 0; j < 64; ++j) bits |= (u64)(buf[(w * 64 + j) * 9 + k] >= 0.f) << j;
                a.dst[l][(size_t)(k * CW + w) * a.Co[l] + row] = bits;
            } else {
                for (int j = 0; j < 64; ++j) bits |= (u64)(buf[t * 64 + j] >= 0.f) << j;
                a.dst[l][(size_t)row * CW + t] = bits;
            }
        }
        return;
    }

    // ---- conv0 path (verbatim round-0 conv0_lane, flat smem indexing) ----
    const int lane = threadIdx.x & 63;
    const int wave = threadIdx.x >> 6;
    float ws[27];
#pragma unroll
    for (int j = 0; j < 27; ++j) ws[j] = (wgt[lane * 27 + j] >= 0.f) ? 1.f : -1.f;

    const int gp0 = blockIdx.x * 32;
    const int n = gp0 >> 8;
    const int ypA = (gp0 >> 4) & 15;
    const int yb = 2 * ypA - 1;

    float* simg = (float*)smem;            // [3][6][34] = 612 floats (2448 B)
    double* sh1 = (double*)(smem + 4096);  // [4][64] (2048 B)
    double* sh2 = (double*)(smem + 6144);  // [4][64] (2048 B)

    const float* xb = x + (size_t)n * 3072;
    for (int t = threadIdx.x; t < 612; t += 256) {
        int ci = t / 204;
        int rem = t % 204;
        int r = rem / 34;
        int cc = rem % 34;
        int yy = yb + r;
        int xx = cc - 1;
        float v = 0.f;
        if ((unsigned)yy < 32u && (unsigned)xx < 32u) v = xb[(ci * 32 + yy) * 32 + xx];
        simg[(ci * 6 + r) * 34 + cc] = v;
    }
    __syncthreads();

    double s1 = 0.0, s2 = 0.0;
#pragma unroll 2
    for (int pi = 0; pi < 8; ++pi) {
        const int lp = wave * 8 + pi;
        const int gp = gp0 + lp;
        const int xp = lp & 15;
        const int rbase = 2 * (lp >> 4);
        const int cbase = 2 * xp;
        float win[3][4][4];
#pragma unroll
        for (int ci = 0; ci < 3; ++ci)
#pragma unroll
            for (int r = 0; r < 4; ++r)
#pragma unroll
                for (int c = 0; c < 4; ++c) win[ci][r][c] = simg[(ci * 6 + rbase + r) * 34 + cbase + c];
        float a00 = 0.f, a01 = 0.f, a10 = 0.f, a11 = 0.f;
#pragma unroll
        for (int ci = 0; ci < 3; ++ci)
#pragma unroll
            for (int ky = 0; ky < 3; ++ky)
#pragma unroll
                for (int kx = 0; kx < 3; ++kx) {
                    float wv = ws[ci * 9 + ky * 3 + kx];
                    a00 += win[ci][ky][kx] * wv;
                    a01 += win[ci][ky][kx + 1] * wv;
                    a10 += win[ci][ky + 1][kx] * wv;
                    a11 += win[ci][ky + 1][kx + 1] * wv;
                }
        float val = fmaxf(fmaxf(a00, a01), fmaxf(a10, a11));
        out[(size_t)gp * 64 + lane] = val;
        s1 += (double)val;
        s2 += (double)val * (double)val;
    }
    sh1[wave * 64 + lane] = s1;
    sh2[wave * 64 + lane] = s2;
    __syncthreads();
    if (threadIdx.x < 64) {
        double t1 = 0.0, t2 = 0.0;
#pragma unroll
        for (int r = 0; r < 4; ++r) {
            t1 += sh1[r * 64 + threadIdx.x];
            t2 += sh2[r * 64 + threadIdx.x];
        }
        double* sh = dacc + (size_t)(blockIdx.x & 7) * 1024;
        atomicAdd(&sh[2 * threadIdx.x], t1);
        atomicAdd(&sh[2 * threadIdx.x + 1], t2);
    }
}

// ================= bnpack float (layer 0), 4-way word split, fused thresholds =================
// 4 threads per output word: each reads 16 floats (64 B), shuffle-OR combine.
__global__ __launch_bounds__(256) void bnpack_f(const float* __restrict__ in,
                                                const double* __restrict__ dacc,
                                                const float* __restrict__ g,
                                                const float* __restrict__ b,
                                                u64* __restrict__ act, int count) {
    __shared__ float2 sthr[64];
    if (threadIdx.x < 64) {
        int i = threadIdx.x;
        double S1 = 0.0, S2 = 0.0;
#pragma unroll
        for (int s = 0; s < 8; ++s) {
            S1 += dacc[s * 1024 + 2 * i];
            S2 += dacc[s * 1024 + 2 * i + 1];
        }
        double m = S1 / count;
        double var = S2 / count - m * m;
        double sc = (double)g[i] / sqrt(var + EPSV);
        float2 r;
        if (sc == 0.0) r = make_float2(b[i] >= 0.f ? -3.0e38f : 3.0e38f, 1.f);
        else {
            double t = m - (double)b[i] / sc;
            r = make_float2((float)t, sc > 0.0 ? 1.f : -1.f);
        }
        sthr[i] = r;
    }
    __syncthreads();
    int tid = blockIdx.x * 256 + threadIdx.x;
    int part = tid & 3;
    int word = tid >> 2;
    const float4* r4 = (const float4*)(in + (size_t)word * 64 + part * 16);
    u64 bits = 0;
#pragma unroll
    for (int q = 0; q < 4; ++q) {
        float4 v = r4[q];
        float vv[4] = {v.x, v.y, v.z, v.w};
#pragma unroll
        for (int u = 0; u < 4; ++u) {
            int c = part * 16 + q * 4 + u;
            float2 t = sthr[c];
            bool bit = (t.y > 0.f) ? (vv[u] >= t.x) : (vv[u] <= t.x);
            bits |= (u64)bit << c;
        }
    }
    bits |= __shfl_xor(bits, 1);
    bits |= __shfl_xor(bits, 2);
    if (part == 0) act[word] = bits;
}

// ================= bnpack int16, 4-way word split, padded threshold table =================
__global__ __launch_bounds__(256) void bnpack_i(const short* __restrict__ in,
                                                const u64* __restrict__ iacc,
                                                const float* __restrict__ g,
                                                const float* __restrict__ b,
                                                u64* __restrict__ act, int Co, int wshift,
                                                int count) {
    __shared__ int2 sthr[520];  // stride 65 breaks the 8-way bank conflict
    for (int i = threadIdx.x; i < Co; i += 256) {
        long long S1 = 0, S2 = 0;
#pragma unroll
        for (int s = 0; s < 8; ++s) {
            S1 += (long long)iacc[s * 1024 + 2 * i];
            S2 += (long long)iacc[s * 1024 + 2 * i + 1];
        }
        double m = (double)S1 / count;
        double var = (double)S2 / count - m * m;
        double sc = (double)g[i] / sqrt(var + EPSV);
        int2 r;
        if (sc == 0.0) r = make_int2(b[i] >= 0.f ? (int)0x80000000 : 0x7fffffff, 0);
        else {
            double t = m - (double)b[i] / sc;
            if (t > 1.0e9) t = 1.0e9;
            if (t < -1.0e9) t = -1.0e9;
            r = (sc > 0.0) ? make_int2((int)ceil(t), 0) : make_int2((int)floor(t), 1);
        }
        sthr[(i >> 6) * 65 + (i & 63)] = r;
    }
    __syncthreads();
    int tid = blockIdx.x * 256 + threadIdx.x;
    int part = tid & 3;
    int word = tid >> 2;
    int w = word & ((1 << wshift) - 1);
    int pix = word >> wshift;
    const int4* r4 = (const int4*)(in + (size_t)pix * Co + (w << 6) + part * 16);
    u64 bits = 0;
#pragma unroll
    for (int q = 0; q < 2; ++q) {
        int4 v = r4[q];
        int words4[4] = {v.x, v.y, v.z, v.w};
#pragma unroll
        for (int u = 0; u < 4; ++u) {
#pragma unroll
            for (int h = 0; h < 2; ++h) {
                int c = part * 16 + q * 8 + u * 2 + h;
                int val = (int)(short)((h == 0) ? (words4[u] & 0xffff) : ((unsigned)words4[u] >> 16));
                int2 t = sthr[w * 65 + c];
                bool bit = t.y ? (val <= t.x) : (val >= t.x);
                bits |= (u64)bit << c;
            }
        }
    }
    bits |= __shfl_xor(bits, 1);
    bits |= __shfl_xor(bits, 2);
    if (part == 0) act[word] = bits;
}

// ================= row-sliding binary conv, lane=co (layers 1..4) =================
// Wave = one output row (HP px); weights amortized over the row; sliding window
// registers. All array indices compile-time literals (dynamic index => scratch
// spill). INTERIOR: no per-tap selects (wave-uniform split).
template <int CW, int HIN, bool POOL, int WC, bool INTERIOR>
__device__ __forceinline__ void row_accum(const u64* __restrict__ inb,
                                          const u64* __restrict__ wpkT, int Co, int co,
                                          const int* yoff, const bool* ry, int* acc) {
    constexpr int HP = POOL ? HIN / 2 : HIN;
    constexpr int WS = POOL ? 4 : 3;
    constexpr int NA = POOL ? 4 : 1;
#pragma unroll 1
    for (int w0 = 0; w0 < CW; w0 += WC) {
        u64 wg[9 * WC];
#pragma unroll
        for (int k = 0; k < 9; ++k)
#pragma unroll
            for (int w = 0; w < WC; ++w)
                wg[k * WC + w] = wpkT[(size_t)(k * CW + w0 + w) * Co + co];
        u64 cur[WS][WS][WC];
#pragma unroll
        for (int d = 0; d < WS; ++d) {
            int cc = d - 1;
            int ccc = cc < 0 ? 0 : cc;
#pragma unroll
            for (int r = 0; r < WS; ++r) {
                const u64* p = inb + yoff[r] + ccc * CW + w0;
                if (WC == 1) {
                    cur[r][d][0] = p[0];
                } else {
                    ulonglong2 v = *(const ulonglong2*)p;
                    cur[r][d][0] = v.x;
                    cur[r][d][1] = v.y;
                }
            }
        }
#pragma unroll
        for (int xp = 0; xp < HP; ++xp) {
            if constexpr (POOL) {
#pragma unroll
                for (int py = 0; py < 2; ++py)
#pragma unroll
                    for (int qx = 0; qx < 2; ++qx)
#pragma unroll
                        for (int ky = 0; ky < 3; ++ky)
#pragma unroll
                            for (int kx = 0; kx < 3; ++kx) {
                                int d = qx + kx;
                                int cc = 2 * xp + d - 1;
                                if (cc >= 0 && cc < HIN) {  // folds (xp,d literal)
#pragma unroll
                                    for (int w = 0; w < WC; ++w) {
                                        int pcv = 64 - 2 * (int)__popcll(cur[py + ky][d][w] ^
                                                                         wg[(ky * 3 + kx) * WC + w]);
                                        if constexpr (INTERIOR)
                                            acc[xp * NA + py * 2 + qx] += pcv;
                                        else
                                            acc[xp * NA + py * 2 + qx] += ry[py + ky] ? pcv : 0;
                                    }
                                }
                            }
            } else {
#pragma unroll
                for (int ky = 0; ky < 3; ++ky)
#pragma unroll
                    for (int kx = 0; kx < 3; ++kx) {
                        int cc = xp + kx - 1;
                        if (cc >= 0 && cc < HIN) {
#pragma unroll
                            for (int w = 0; w < WC; ++w) {
                                int pcv = 64 - 2 * (int)__popcll(cur[ky][kx][w] ^
                                                                 wg[(ky * 3 + kx) * WC + w]);
                                if constexpr (INTERIOR)
                                    acc[xp] += pcv;
                                else
                                    acc[xp] += ry[ky] ? pcv : 0;
                            }
                        }
                    }
            }
            if (xp < HP - 1) {
                if constexpr (POOL) {
#pragma unroll
                    for (int r = 0; r < WS; ++r)
#pragma unroll
                        for (int w = 0; w < WC; ++w) {
                            cur[r][0][w] = cur[r][2][w];
                            cur[r][1][w] = cur[r][3][w];
                        }
#pragma unroll
                    for (int dd = 2; dd < 4; ++dd) {
                        int cc = 2 * (xp + 1) + dd - 1;
                        int ccc = cc >= HIN ? HIN - 1 : cc;
#pragma unroll
                        for (int r = 0; r < WS; ++r) {
                            const u64* p = inb + yoff[r] + ccc * CW + w0;
                            if (WC == 1) {
                                cur[r][dd][0] = p[0];
                            } else {
                                ulonglong2 v = *(const ulonglong2*)p;
                                cur[r][dd][0] = v.x;
                                cur[r][dd][1] = v.y;
                            }
                        }
                    }
                } else {
#pragma unroll
                    for (int r = 0; r < WS; ++r)
#pragma unroll
                        for (int w = 0; w < WC; ++w) {
                            cur[r][0][w] = cur[r][1][w];
                            cur[r][1][w] = cur[r][2][w];
                        }
                    int cc = xp + 2;
                    int ccc = cc >= HIN ? HIN - 1 : cc;
#pragma unroll
                    for (int r = 0; r < WS; ++r) {
                        const u64* p = inb + yoff[r] + ccc * CW + w0;
                        if (WC == 1) {
                            cur[r][2][0] = p[0];
                        } else {
                            ulonglong2 v = *(const ulonglong2*)p;
                            cur[r][2][0] = v.x;
                            cur[r][2][1] = v.y;
                        }
                    }
                }
            }
        }
    }
}

template <int CW, int HIN, bool POOL, int WC>
__global__ __launch_bounds__(256) void bconv_row(const u64* __restrict__ in,
                                                 const u64* __restrict__ wpkT,
                                                 short* __restrict__ out,
                                                 u64* __restrict__ iacc, int Co) {
    constexpr int HP = POOL ? HIN / 2 : HIN;
    constexpr int WS = POOL ? 4 : 3;
    constexpr int NA = POOL ? 4 : 1;
    const int lane = threadIdx.x & 63;
    const int co = blockIdx.y * 64 + lane;
    const int grow = blockIdx.x * 4 + (threadIdx.x >> 6);  // n*HP + yp
    const int n = grow / HP;
    const int yp = grow % HP;
    const int y0 = (POOL ? 2 * yp : yp) - 1;
    const u64* inb = in + (size_t)n * (HIN * HIN * CW);
    int yoff[WS];
    bool ry[WS];
#pragma unroll
    for (int r = 0; r < WS; ++r) {
        int y = y0 + r;
        ry[r] = (unsigned)y < (unsigned)HIN;
        int yc = iclamp(y, 0, HIN - 1);
        yoff[r] = yc * HIN * CW;
    }
    int acc[HP * NA];
#pragma unroll
    for (int i = 0; i < HP * NA; ++i) acc[i] = 0;

    if (yp > 0 && yp < HP - 1)
        row_accum<CW, HIN, POOL, WC, true>(inb, wpkT, Co, co, yoff, ry, acc);
    else
        row_accum<CW, HIN, POOL, WC, false>(inb, wpkT, Co, co, yoff, ry, acc);

    int s1 = 0;
    long long s2 = 0;
    short* orow = out + (size_t)grow * HP * Co + co;
#pragma unroll
    for (int xp = 0; xp < HP; ++xp) {
        int ival;
        if constexpr (POOL)
            ival = imax(imax(acc[xp * 4], acc[xp * 4 + 1]), imax(acc[xp * 4 + 2], acc[xp * 4 + 3]));
        else
            ival = acc[xp];
        orow[(size_t)xp * Co] = (short)ival;
        s1 += ival;
        s2 += (long long)ival * ival;
    }

    __shared__ u64 sacc[128];
    if (threadIdx.x < 128) sacc[threadIdx.x] = 0ULL;
    __syncthreads();
    atomicAdd(&sacc[lane], (u64)(long long)s1);
    atomicAdd(&sacc[64 + lane], (u64)s2);
    __syncthreads();
    u64* sh = iacc + (size_t)(blockIdx.x & 7) * 1024;
    if (threadIdx.x < 64)
        atomicAdd(&sh[2 * (blockIdx.y * 64 + threadIdx.x)], sacc[threadIdx.x]);
    else if (threadIdx.x < 128)
        atomicAdd(&sh[2 * (blockIdx.y * 64 + threadIdx.x - 64) + 1], sacc[threadIdx.x]);
}

// ================= binary conv for tiny images (layers 5..7, HIN in {2,4}) =================
template <int CW, int HIN, bool POOL>
__global__ __launch_bounds__(256) void bconv_tiny(const u64* __restrict__ in,
                                                  const u64* __restrict__ wpkT,
                                                  short* __restrict__ out,
                                                  u64* __restrict__ iacc, int Co) {
    constexpr int NPX = HIN * HIN;
    constexpr int HP = POOL ? HIN / 2 : HIN;
    const int lane = threadIdx.x & 63;
    const int co = blockIdx.y * 64 + lane;
    const int n = blockIdx.x * 4 + (threadIdx.x >> 6);
    const u64* inb = in + (size_t)n * CW * NPX;
    int acc[NPX];
#pragma unroll
    for (int i = 0; i < NPX; ++i) acc[i] = 0;

#pragma unroll 2
    for (int w = 0; w < CW; ++w) {
        u64 win[NPX];
#pragma unroll
        for (int i = 0; i < NPX; ++i) win[i] = inb[i * CW + w];
#pragma unroll
        for (int k = 0; k < 9; ++k) {
            u64 wb = wpkT[(size_t)(k * CW + w) * Co + co];
            const int ky = k / 3, kx = k % 3;
#pragma unroll
            for (int py = 0; py < HIN; ++py)
#pragma unroll
                for (int px = 0; px < HIN; ++px) {
                    const int yy = py + ky - 1, xx = px + kx - 1;
                    if (yy >= 0 && yy < HIN && xx >= 0 && xx < HIN)
                        acc[py * HIN + px] += 64 - 2 * (int)__popcll(win[yy * HIN + xx] ^ wb);
                }
        }
    }

    short vals[HP * HP];
    if constexpr (POOL) {
#pragma unroll
        for (int py = 0; py < HP; ++py)
#pragma unroll
            for (int px = 0; px < HP; ++px)
                vals[py * HP + px] = (short)imax(
                    imax(acc[(2 * py) * HIN + 2 * px], acc[(2 * py) * HIN + 2 * px + 1]),
                    imax(acc[(2 * py + 1) * HIN + 2 * px], acc[(2 * py + 1) * HIN + 2 * px + 1]));
    } else {
#pragma unroll
        for (int i = 0; i < NPX; ++i) vals[i] = (short)acc[i];
    }
#pragma unroll
    for (int p = 0; p < HP * HP; ++p) out[(size_t)(n * HP * HP + p) * Co + co] = vals[p];

    long long s1 = 0, s2 = 0;
#pragma unroll
    for (int p = 0; p < HP * HP; ++p) {
        s1 += vals[p];
        s2 += (long long)vals[p] * vals[p];
    }
    __shared__ u64 sacc[128];
    if (threadIdx.x < 128) sacc[threadIdx.x] = 0ULL;
    __syncthreads();
    atomicAdd(&sacc[lane], (u64)s1);
    atomicAdd(&sacc[64 + lane], (u64)s2);
    __syncthreads();
    u64* sh = iacc + (size_t)(blockIdx.x & 7) * 1024;
    if (threadIdx.x < 64)
        atomicAdd(&sh[2 * (blockIdx.y * 64 + threadIdx.x)], sacc[threadIdx.x]);
    else if (threadIdx.x < 128)
        atomicAdd(&sh[2 * (blockIdx.y * 64 + threadIdx.x - 64) + 1], sacc[threadIdx.x]);
}

// ================= binarized linear + BN1 (+ hardtanh) =================
__global__ __launch_bounds__(256) void lin_kernel(const u64* __restrict__ hp,
                                                  const u64* __restrict__ wp,
                                                  const float* __restrict__ lb,
                                                  const float* __restrict__ g,
                                                  const float* __restrict__ bta,
                                                  float* __restrict__ z, int O, int applyHt) {
    int o = blockIdx.x;
    int n = threadIdx.x;
    const u64* hr = hp + n * 8;
    const u64* wr = wp + o * 8;
    int s = 0;
#pragma unroll
    for (int w = 0; w < 8; ++w) s += (int)__popcll(hr[w] ^ wr[w]);
    float val = (float)(512 - 2 * s) + lb[o];
    __shared__ double sh1[256], sh2[256];
    sh1[n] = (double)val;
    sh2[n] = (double)val * (double)val;
    __syncthreads();
    for (int st = 128; st > 0; st >>= 1) {
        if (n < st) {
            sh1[n] += sh1[n + st];
            sh2[n] += sh2[n + st];
        }
        __syncthreads();
    }
    __shared__ float sm, siv;
    if (n == 0) {
        double m = sh1[0] / 256.0;
        double var = sh2[0] / 256.0 - m * m;
        sm = (float)m;
        siv = (float)(1.0 / sqrt(var + EPSV));
    }
    __syncthreads();
    float zz = g[o] * (val - sm) * siv + bta[o];
    if (applyHt) zz = fminf(1.f, fmaxf(-1.f, zz));
    z[(size_t)n * O + o] = zz;
}

// pack post-ht FC activations [256,512] -> [256,8], 4-way word split
__global__ void pack_rows(const float* __restrict__ z, u64* __restrict__ hp) {
    int tid = blockIdx.x * 256 + threadIdx.x;  // 8192 total
    int part = tid & 3;
    int word = tid >> 2;
    int ww = word & 7;
    int n = word >> 3;
    const float4* r4 = (const float4*)(z + (size_t)n * 512 + (ww << 6) + part * 16);
    u64 bits = 0;
#pragma unroll
    for (int q = 0; q < 4; ++q) {
        float4 v = r4[q];
        float vv[4] = {v.x, v.y, v.z, v.w};
#pragma unroll
        for (int u = 0; u < 4; ++u) bits |= (u64)(vv[u] >= 0.f) << (part * 16 + q * 4 + u);
    }
    bits |= __shfl_xor(bits, 1);
    bits |= __shfl_xor(bits, 2);
    if (part == 0) hp[word] = bits;
}

__global__ void lsm_kernel(const float* __restrict__ z, float* __restrict__ out) {
    int n = blockIdx.x * 64 + threadIdx.x;
    if (n >= 256) return;
    float v[10];
    float m = -1e30f;
#pragma unroll
    for (int i = 0; i < 10; ++i) {
        v[i] = z[n * 10 + i];
        m = fmaxf(m, v[i]);
    }
    float s = 0.f;
#pragma unroll
    for (int i = 0; i < 10; ++i) s += expf(v[i] - m);
    float ls = logf(s);
#pragma unroll
    for (int i = 0; i < 10; ++i) out[n * 10 + i] = v[i] - m - ls;
}

extern "C" void kernel_launch(void* const* d_in, const int* in_sizes, int n_in, void* d_out,
                              int out_size, void* d_ws, size_t ws_size, hipStream_t stream) {
    (void)in_sizes; (void)n_in; (void)out_size; (void)ws_size;
    const float* x = (const float*)d_in[0];
    const float *cw[8], *cb[8], *cg[8], *ct[8];
    for (int i = 0; i < 8; ++i) {
        cw[i] = (const float*)d_in[1 + 4 * i];
        cb[i] = (const float*)d_in[2 + 4 * i];
        cg[i] = (const float*)d_in[3 + 4 * i];
        ct[i] = (const float*)d_in[4 + 4 * i];
    }
    const float *lw[3], *lb[3], *lg[3], *lt[3];
    for (int i = 0; i < 3; ++i) {
        lw[i] = (const float*)d_in[33 + 4 * i];
        lb[i] = (const float*)d_in[34 + 4 * i];
        lg[i] = (const float*)d_in[35 + 4 * i];
        lt[i] = (const float*)d_in[36 + 4 * i];
    }

    static const int CIs[8] = {3, 64, 128, 256, 256, 512, 512, 512};
    static const int COs[8] = {64, 128, 256, 256, 512, 512, 512, 512};
    static const int HPs[8] = {16, 8, 8, 4, 4, 2, 2, 1};

    char* ws = (char*)d_ws;
    size_t off = 0;
    auto alloc = [&](size_t bytes) -> void* {
        void* p = ws + off;
        off += (bytes + 255) & ~(size_t)255;
        return p;
    };

    u64* wpkT[8] = {};
    for (int i = 1; i < 8; ++i) wpkT[i] = (u64*)alloc((size_t)COs[i] * 9 * (CIs[i] / 64) * 8);
    u64* wpl[3];
    int LO[3] = {512, 512, 10};
    for (int i = 0; i < 3; ++i) wpl[i] = (u64*)alloc((size_t)LO[i] * 8 * 8);
    u64* act[8];
    for (int i = 0; i < 8; ++i) act[i] = (u64*)alloc((size_t)256 * (COs[i] / 64) * HPs[i] * HPs[i] * 8);
    u64* fcs0 = (u64*)alloc(2048 * 8);
    u64* fcs1 = (u64*)alloc(2048 * 8);
    float* out0 = (float*)alloc((size_t)65536 * 64 * 4);
    short* i16A = (short*)alloc((size_t)16384 * 256 * 2);
    short* i16B = (short*)alloc((size_t)16384 * 256 * 2);
    float* z0 = (float*)alloc((size_t)256 * 512 * 4);
    float* z1 = (float*)alloc((size_t)256 * 512 * 4);
    float* z2 = (float*)alloc((size_t)256 * 10 * 4);
    // sharded stats: 8 layers x 8 shards x 1024 u64 (layer0 = doubles)
    u64* accs = (u64*)alloc((size_t)8 * 8 * 1024 * 8);
    double* dacc0 = (double*)accs;
    auto iacc = [&](int layer) { return accs + (size_t)layer * 8192; };

    // ---- zero stats (stream-ordered, graph-capture-safe) ----
    hipMemsetAsync(accs, 0, (size_t)8 * 8 * 1024 * 8, stream);

    // ---- fused prep + conv0 ----
    PrepArgs pa;
    int rb = 0;
    for (int i = 1; i < 8; ++i) {
        int e = i - 1;
        pa.src[e] = cw[i];
        pa.dst[e] = wpkT[i];
        pa.CW[e] = CIs[i] / 64;
        pa.Co[e] = COs[i];
        pa.taps[e] = 9;
        pa.rowbase[e] = rb;
        rb += COs[i];
    }
    for (int i = 0; i < 3; ++i) {
        int e = 7 + i;
        pa.src[e] = lw[i];
        pa.dst[e] = wpl[i];
        pa.CW[e] = 8;
        pa.Co[e] = LO[i];
        pa.taps[e] = 1;
        pa.rowbase[e] = rb;
        rb += LO[i];
    }
    pa.rowbase[10] = rb;  // 3722
    prep_conv0<<<2048 + rb, 256, 0, stream>>>(pa, x, cw[0], out0, dacc0);

    // ---- L0 pack ----
    bnpack_f<<<1024, 256, 0, stream>>>(out0, dacc0, cg[0], ct[0], act[0], 65536);

    // ---- L1: 64ch 16x16 -> 128ch, pool -> 8x8 ----
    bconv_row<1, 16, true, 1><<<dim3(512, 2), 256, 0, stream>>>(act[0], wpkT[1], i16A, iacc(1), 128);
    bnpack_i<<<512, 256, 0, stream>>>(i16A, iacc(1), cg[1], ct[1], act[1], 128, 1, 16384);

    // ---- L2: 128ch 8x8 -> 256ch ----
    bconv_row<2, 8, false, 2><<<dim3(512, 4), 256, 0, stream>>>(act[1], wpkT[2], i16B, iacc(2), 256);
    bnpack_i<<<1024, 256, 0, stream>>>(i16B, iacc(2), cg[2], ct[2], act[2], 256, 2, 16384);

    // ---- L3: 256ch 8x8 -> 256ch, pool -> 4x4 ----
    bconv_row<4, 8, true, 2><<<dim3(256, 4), 256, 0, stream>>>(act[2], wpkT[3], i16A, iacc(3), 256);
    bnpack_i<<<256, 256, 0, stream>>>(i16A, iacc(3), cg[3], ct[3], act[3], 256, 2, 4096);

    // ---- L4: 256ch 4x4 -> 512ch ----
    bconv_row<4, 4, false, 2><<<dim3(256, 8), 256, 0, stream>>>(act[3], wpkT[4], i16B, iacc(4), 512);
    bnpack_i<<<512, 256, 0, stream>>>(i16B, iacc(4), cg[4], ct[4], act[4], 512, 3, 4096);

    // ---- L5: 512ch 4x4 -> 512ch, pool -> 2x2 (tiny) ----
    bconv_tiny<8, 4, true><<<dim3(64, 8), 256, 0, stream>>>(act[4], wpkT[5], i16A, iacc(5), 512);
    bnpack_i<<<128, 256, 0, stream>>>(i16A, iacc(5), cg[5], ct[5], act[5], 512, 3, 1024);

    // ---- L6: 512ch 2x2 -> 512ch (tiny) ----
    bconv_tiny<8, 2, false><<<dim3(64, 8), 256, 0, stream>>>(act[5], wpkT[6], i16B, iacc(6), 512);
    bnpack_i<<<128, 256, 0, stream>>>(i16B, iacc(6), cg[6], ct[6], act[6], 512, 3, 1024);

    // ---- L7: 512ch 2x2 -> 512ch, pool -> 1x1 (tiny) ----
    bconv_tiny<8, 2, true><<<dim3(64, 8), 256, 0, stream>>>(act[6], wpkT[7], i16A, iacc(7), 512);
    bnpack_i<<<32, 256, 0, stream>>>(i16A, iacc(7), cg[7], ct[7], act[7], 512, 3, 256);

    // ---- FC ----
    lin_kernel<<<512, 256, 0, stream>>>(act[7], wpl[0], lb[0], lg[0], lt[0], z0, 512, 1);
    pack_rows<<<32, 256, 0, stream>>>(z0, fcs0);
    lin_kernel<<<512, 256, 0, stream>>>(fcs0, wpl[1], lb[1], lg[1], lt[1], z1, 512, 1);
    pack_rows<<<32, 256, 0, stream>>>(z1, fcs1);
    lin_kernel<<<10, 256, 0, stream>>>(fcs1, wpl[2], lb[2], lg[2], lt[2], z2, 10, 0);
    lsm_kernel<<<4, 64, 0, stream>>>(z2, (float*)d_out);
}